// Round 3
// baseline (854.906 us; speedup 1.0000x reference)
//
#include <hip/hip_runtime.h>
#include <math.h>

#define SELU_LAMBDA 1.0507009873554805f
#define SELU_ALPHA  1.6732632423543772f

#define BSHIFT 9
#define BNODES 512          // nodes per bucket
#define CAP    10240        // bucket capacity (mean 8192, +22 sigma)
#define CHUNK  4096         // edges per k_bin block

// ---------------------------------------------------------------- phase 1: bin edges by dst bucket
// packed entry: src | (dstLocal << 17)   (src < 2^17, dstLocal < 2^9)
__global__ __launch_bounds__(256) void k_bin(const int* __restrict__ src,
    const int* __restrict__ dst, int* __restrict__ cursor,
    int* __restrict__ binned, int e) {
  __shared__ int hist[256];
  __shared__ int gb[256];
  const int tid = threadIdx.x;
  hist[tid] = 0;
  __syncthreads();
  const int base = blockIdx.x * CHUNK;
  int bk[16], rk[16], pk[16];
#pragma unroll
  for (int k = 0; k < 16; ++k) {
    int i = base + k * 256 + tid;
    if (i < e) {
      int d = dst[i];
      int s = src[i];
      int b = d >> BSHIFT;
      bk[k] = b;
      pk[k] = s | ((d & (BNODES - 1)) << 17);
      rk[k] = atomicAdd(&hist[b], 1);
    } else {
      bk[k] = -1;
    }
  }
  __syncthreads();
  int h = hist[tid];
  if (h > 0) gb[tid] = atomicAdd(&cursor[tid], h);
  __syncthreads();
#pragma unroll
  for (int k = 0; k < 16; ++k) {
    if (bk[k] >= 0) binned[bk[k] * CAP + gb[bk[k]] + rk[k]] = pk[k];
  }
}

// ---------------------------------------------------------------- phase 2: scan bucket counts
__global__ __launch_bounds__(256) void k_bucket_scan(const int* __restrict__ cursor,
    int* __restrict__ csrBase, int* __restrict__ offs, int nb, int n, int e) {
  __shared__ int buf[2][256];
  const int tid = threadIdx.x;
  int v = (tid < nb) ? cursor[tid] : 0;
  buf[0][tid] = v;
  __syncthreads();
  int cur = 0;
  for (int d = 1; d < 256; d <<= 1) {
    int t = buf[cur][tid];
    if (tid >= d) t += buf[cur][tid - d];
    buf[cur ^ 1][tid] = t;
    cur ^= 1;
    __syncthreads();
  }
  if (tid < nb) csrBase[tid] = (tid == 0) ? 0 : buf[cur][tid - 1];
  if (tid == 0) {
    csrBase[nb] = e;
    offs[n] = e;
  }
}

// ---------------------------------------------------------------- phase 3: per-bucket CSR build (one wg owns one bucket)
__global__ __launch_bounds__(256) void k_build(const int* __restrict__ binned,
    const int* __restrict__ csrBase, int* __restrict__ offs,
    int* __restrict__ csr, int n) {
  __shared__ int deg[BNODES];
  __shared__ int pre[BNODES];
  __shared__ int wsum[4];
  __shared__ int stage[CAP];
  const int b = blockIdx.x;
  const int tid = threadIdx.x;
  const int nodeBase = b << BSHIFT;
  const int cbase = csrBase[b];
  const int cnt = csrBase[b + 1] - cbase;
  const int* gsrc = binned + b * CAP;

  deg[tid] = 0;
  deg[tid + 256] = 0;
  __syncthreads();
  for (int i = tid; i < cnt; i += 256) atomicAdd(&deg[gsrc[i] >> 17], 1);
  __syncthreads();

  // exclusive scan of deg[512]: 2 elements/thread
  const int lane = tid & 63, w = tid >> 6;
  int a0 = deg[2 * tid], a1 = deg[2 * tid + 1];
  int ps = a0 + a1;
  int s = ps;
#pragma unroll
  for (int d = 1; d < 64; d <<= 1) {
    int t = __shfl_up(s, d, 64);
    if (lane >= d) s += t;
  }
  if (lane == 63) wsum[w] = s;
  __syncthreads();
  if (tid == 0) {
    int acc = 0;
#pragma unroll
    for (int j = 0; j < 4; ++j) { int t = wsum[j]; wsum[j] = acc; acc += t; }
  }
  __syncthreads();
  int ex = wsum[w] + s - ps;
  pre[2 * tid] = ex;
  pre[2 * tid + 1] = ex + a0;
  // reset deg for use as cursor
  deg[tid] = 0;
  deg[tid + 256] = 0;
  __syncthreads();

  const int nNodes = min(BNODES, n - nodeBase);
  for (int i = tid; i < nNodes; i += 256) offs[nodeBase + i] = cbase + pre[i];

  for (int i = tid; i < cnt; i += 256) {
    int v = gsrc[i];
    int dl = v >> 17;
    int p = pre[dl] + atomicAdd(&deg[dl], 1);
    stage[p] = v & 0x1FFFF;
  }
  __syncthreads();
  for (int i = tid; i < cnt; i += 256) csr[cbase + i] = stage[i];
}

// ---------------------------------------------------------------- GEMM1: X(Nx128) @ W1(128x64) -> H(Nx64), no bias
__global__ __launch_bounds__(256) void k_gemm1(
    const float* __restrict__ A, const float* __restrict__ W1,
    float* __restrict__ H, int n) {
  __shared__ float Ws[128 * 64];
  for (int t = threadIdx.x; t < 128 * 64; t += 256) Ws[t] = W1[t];
  __syncthreads();

  const int rg = threadIdx.x >> 4;
  const int c0 = (threadIdx.x & 15) * 4;
  const int row0 = blockIdx.x * 64 + rg * 4;

  float acc[4][4] = {};
  for (int k = 0; k < 128; k += 4) {
    float4 a[4];
#pragma unroll
    for (int r = 0; r < 4; ++r) {
      int row = row0 + r;
      int rowc = row < n ? row : n - 1;
      a[r] = *(const float4*)&A[(size_t)rowc * 128 + k];
    }
    float4 w0 = *(const float4*)&Ws[(k + 0) * 64 + c0];
    float4 w1 = *(const float4*)&Ws[(k + 1) * 64 + c0];
    float4 w2 = *(const float4*)&Ws[(k + 2) * 64 + c0];
    float4 w3 = *(const float4*)&Ws[(k + 3) * 64 + c0];
#pragma unroll
    for (int r = 0; r < 4; ++r) {
      acc[r][0] += a[r].x * w0.x + a[r].y * w1.x + a[r].z * w2.x + a[r].w * w3.x;
      acc[r][1] += a[r].x * w0.y + a[r].y * w1.y + a[r].z * w2.y + a[r].w * w3.y;
      acc[r][2] += a[r].x * w0.z + a[r].y * w1.z + a[r].z * w2.z + a[r].w * w3.z;
      acc[r][3] += a[r].x * w0.w + a[r].y * w1.w + a[r].z * w2.w + a[r].w * w3.w;
    }
  }
#pragma unroll
  for (int r = 0; r < 4; ++r) {
    int row = row0 + r;
    if (row < n) {
      *(float4*)&H[(size_t)row * 64 + c0] =
          make_float4(acc[r][0], acc[r][1], acc[r][2], acc[r][3]);
    }
  }
}

// ---------------------------------------------------------------- hop at D=64: one wave per node (4 edges in flight)
__global__ __launch_bounds__(256) void k_hop64(const float* __restrict__ hin,
    float* __restrict__ hout, const int* __restrict__ offs,
    const int* __restrict__ csr, int n) {
  int wid = (blockIdx.x * 256 + threadIdx.x) >> 6;
  if (wid >= n) return;
  int lane = threadIdx.x & 63;
  int beg = offs[wid], end = offs[wid + 1];
  size_t base = (size_t)wid * 64 + lane;
  float acc = hin[base];
  int e = beg;
  for (; e + 3 < end; e += 4) {
    int j0 = csr[e], j1 = csr[e + 1], j2 = csr[e + 2], j3 = csr[e + 3];
    float v0 = hin[(size_t)j0 * 64 + lane];
    float v1 = hin[(size_t)j1 * 64 + lane];
    float v2 = hin[(size_t)j2 * 64 + lane];
    float v3 = hin[(size_t)j3 * 64 + lane];
    acc += (v0 + v1) + (v2 + v3);
  }
  for (; e < end; ++e) acc += hin[(size_t)csr[e] * 64 + lane];
  hout[base] = acc;
}

// second hop fused with per-column (sum, sumsq) batch stats
__global__ __launch_bounds__(256) void k_hop64_stats(const float* __restrict__ hin,
    float* __restrict__ hout, const int* __restrict__ offs,
    const int* __restrict__ csr, float* __restrict__ stats, int n) {
  int wid = (blockIdx.x * 256 + threadIdx.x) >> 6;
  int lane = threadIdx.x & 63;
  float acc = 0.f;
  if (wid < n) {
    int beg = offs[wid], end = offs[wid + 1];
    size_t base = (size_t)wid * 64 + lane;
    acc = hin[base];
    int e = beg;
    for (; e + 3 < end; e += 4) {
      int j0 = csr[e], j1 = csr[e + 1], j2 = csr[e + 2], j3 = csr[e + 3];
      float v0 = hin[(size_t)j0 * 64 + lane];
      float v1 = hin[(size_t)j1 * 64 + lane];
      float v2 = hin[(size_t)j2 * 64 + lane];
      float v3 = hin[(size_t)j3 * 64 + lane];
      acc += (v0 + v1) + (v2 + v3);
    }
    for (; e < end; ++e) acc += hin[(size_t)csr[e] * 64 + lane];
    hout[base] = acc;
  }
  __shared__ float l1[4][64];
  __shared__ float l2[4][64];
  const int w = threadIdx.x >> 6;
  float v = (wid < n) ? acc : 0.f;
  l1[w][lane] = v;
  l2[w][lane] = v * v;
  __syncthreads();
  if (threadIdx.x < 64) {
    float t1 = l1[0][lane] + l1[1][lane] + l1[2][lane] + l1[3][lane];
    float t2 = l2[0][lane] + l2[1][lane] + l2[2][lane] + l2[3][lane];
    atomicAdd(&stats[lane], t1);
    atomicAdd(&stats[64 + lane], t2);
  }
}

__global__ void k_finalize_stats(const float* __restrict__ stats,
    const float* __restrict__ bn_w, const float* __restrict__ bn_b,
    float* __restrict__ ab, int n) {
  int f = threadIdx.x;
  if (f < 64) {
    float inv_n = 1.0f / (float)n;
    float mu = stats[f] * inv_n;
    float var = stats[64 + f] * inv_n - mu * mu;
    float s = bn_w[f] * rsqrtf(var + 1e-5f);
    ab[f] = s;
    ab[64 + f] = bn_b[f] - mu * s;
  }
}

// ---------------------------------------------------------------- GEMM2 with fused BN affine + SELU
__global__ __launch_bounds__(256) void k_gemm2(const float* __restrict__ A,
    const float* __restrict__ ab, const float* __restrict__ W2,
    float* __restrict__ Y, int n) {
  int row = blockIdx.x * 256 + threadIdx.x;
  if (row >= n) return;
  float4 acc[4] = {make_float4(0, 0, 0, 0), make_float4(0, 0, 0, 0),
                   make_float4(0, 0, 0, 0), make_float4(0, 0, 0, 0)};
  const float4* A4 = (const float4*)(A + (size_t)row * 64);
#pragma unroll
  for (int k = 0; k < 64; k += 4) {
    float4 a = A4[k >> 2];
    float av[4] = {a.x, a.y, a.z, a.w};
#pragma unroll
    for (int kk = 0; kk < 4; ++kk) {
      float y = ab[k + kk] * av[kk] + ab[64 + k + kk];
      y = y > 0.f ? SELU_LAMBDA * y : SELU_LAMBDA * SELU_ALPHA * expm1f(y);
      const float4* Wr = (const float4*)&W2[(k + kk) * 16];
      float4 w0 = Wr[0], w1 = Wr[1], w2 = Wr[2], w3 = Wr[3];
      acc[0].x += y * w0.x; acc[0].y += y * w0.y; acc[0].z += y * w0.z; acc[0].w += y * w0.w;
      acc[1].x += y * w1.x; acc[1].y += y * w1.y; acc[1].z += y * w1.z; acc[1].w += y * w1.w;
      acc[2].x += y * w2.x; acc[2].y += y * w2.y; acc[2].z += y * w2.z; acc[2].w += y * w2.w;
      acc[3].x += y * w3.x; acc[3].y += y * w3.y; acc[3].z += y * w3.z; acc[3].w += y * w3.w;
    }
  }
  float4* o = (float4*)(Y + (size_t)row * 16);
  o[0] = acc[0]; o[1] = acc[1]; o[2] = acc[2]; o[3] = acc[3];
}

// ---------------------------------------------------------------- hop at D=16 + b2 + log_softmax
__global__ __launch_bounds__(256) void k_hop16(const float* __restrict__ Y,
    const float* __restrict__ b2, float* __restrict__ out,
    const int* __restrict__ offs, const int* __restrict__ csr, int n) {
  int wid = (blockIdx.x * 256 + threadIdx.x) >> 6;
  if (wid >= n) return;
  int lane = threadIdx.x & 63;
  int sub = lane >> 4, dim = lane & 15;
  int beg = offs[wid], end = offs[wid + 1];
  float acc = 0.f;
  for (int e = beg; e < end; e += 8) {
    int i0 = e + sub, i1 = e + 4 + sub;
    float v0 = 0.f, v1 = 0.f;
    if (i0 < end) v0 = Y[(size_t)csr[i0] * 16 + dim];
    if (i1 < end) v1 = Y[(size_t)csr[i1] * 16 + dim];
    acc += v0 + v1;
  }
  acc += __shfl_down(acc, 32, 64);
  acc += __shfl_down(acc, 16, 64);
  float v = acc + Y[(size_t)wid * 16 + dim] + b2[dim];
  float m = v;
#pragma unroll
  for (int d = 8; d >= 1; d >>= 1) m = fmaxf(m, __shfl_xor(m, d, 16));
  float s = expf(v - m);
#pragma unroll
  for (int d = 8; d >= 1; d >>= 1) s += __shfl_xor(s, d, 16);
  float r = v - (m + logf(s));
  if (lane < 16) out[(size_t)wid * 16 + dim] = r;
}

// ---------------------------------------------------------------- launch
extern "C" void kernel_launch(void* const* d_in, const int* in_sizes, int n_in,
                              void* d_out, int out_size, void* d_ws, size_t ws_size,
                              hipStream_t stream) {
  const float* x   = (const float*)d_in[0];
  const int* esrc  = (const int*)d_in[1];
  const int* edst  = (const int*)d_in[2];
  const float* W1  = (const float*)d_in[3];
  // d_in[4] = b1: cancels exactly under batchnorm mean subtraction
  const float* bnw = (const float*)d_in[5];
  const float* bnb = (const float*)d_in[6];
  const float* W2  = (const float*)d_in[7];
  const float* b2  = (const float*)d_in[8];
  float* out = (float*)d_out;

  const int N = in_sizes[0] / 128;  // 100000
  const int E = in_sizes[1];        // 1600000
  const int NB = (N + BNODES - 1) >> BSHIFT;  // 196 buckets

  char* p = (char*)d_ws;
  auto alloc = [&](size_t bytes) {
    char* q = p;
    p += (bytes + 255) & ~(size_t)255;
    return q;
  };
  int* cursor  = (int*)alloc(256 * sizeof(int));
  int* csrBase = (int*)alloc(257 * sizeof(int));
  int* binned  = (int*)alloc((size_t)NB * CAP * sizeof(int));
  int* offs    = (int*)alloc((size_t)(N + 4) * sizeof(int));
  int* csr     = (int*)alloc((size_t)E * sizeof(int));
  float* stats = (float*)alloc(128 * sizeof(float));
  float* ab    = (float*)alloc(128 * sizeof(float));
  float* bufA  = (float*)alloc((size_t)N * 64 * sizeof(float));
  float* bufB  = (float*)alloc((size_t)N * 64 * sizeof(float));
  float* bufC  = (float*)alloc((size_t)N * 16 * sizeof(float));

  hipMemsetAsync(cursor, 0, 256 * sizeof(int), stream);
  hipMemsetAsync(stats, 0, 128 * sizeof(float), stream);

  // CSR build: bin -> scan -> per-bucket build
  k_bin<<<(E + CHUNK - 1) / CHUNK, 256, 0, stream>>>(esrc, edst, cursor, binned, E);
  k_bucket_scan<<<1, 256, 0, stream>>>(cursor, csrBase, offs, NB, N, E);
  k_build<<<NB, 256, 0, stream>>>(binned, csrBase, offs, csr, N);

  // GEMM first (propagation commutes with the linear layer): hops run at D=64
  k_gemm1<<<(N + 63) / 64, 256, 0, stream>>>(x, W1, bufA, N);

  int hopBlocks = (N * 64 + 255) / 256;  // one wave per node
  k_hop64<<<hopBlocks, 256, 0, stream>>>(bufA, bufB, offs, csr, N);
  k_hop64_stats<<<hopBlocks, 256, 0, stream>>>(bufB, bufA, offs, csr, stats, N);

  k_finalize_stats<<<1, 64, 0, stream>>>(stats, bnw, bnb, ab, N);

  // GEMM2 (with fused BN+SELU) before the last hop: hop runs at D=16
  k_gemm2<<<(N + 255) / 256, 256, 0, stream>>>(bufA, ab, W2, bufC, N);
  k_hop16<<<hopBlocks, 256, 0, stream>>>(bufC, b2, out, offs, csr, N);
}

// Round 4
// 319.022 us; speedup vs baseline: 2.6798x; 2.6798x over previous
//
#include <hip/hip_runtime.h>
#include <math.h>

#define SELU_LAMBDA 1.0507009873554805f
#define SELU_ALPHA  1.6732632423543772f

#define BSHIFT 9
#define BNODES 512          // nodes per bucket
#define CAP    10240        // bucket capacity (mean 8192, +22 sigma)
#define CHUNK  4096         // edges per k_bin block
#define NSLOT  64           // stats atomic spreading slots

// ---------------------------------------------------------------- phase 1: bin edges by dst bucket
// packed entry: src | (dstLocal << 17)   (src < 2^17, dstLocal < 2^9)
__global__ __launch_bounds__(256) void k_bin(const int* __restrict__ src,
    const int* __restrict__ dst, int* __restrict__ cursor,
    int* __restrict__ binned, int e) {
  __shared__ int hist[256];
  __shared__ int gb[256];
  const int tid = threadIdx.x;
  hist[tid] = 0;
  __syncthreads();
  const int base = blockIdx.x * CHUNK;
  int bk[16], rk[16], pk[16];
#pragma unroll
  for (int k = 0; k < 16; ++k) {
    int i = base + k * 256 + tid;
    if (i < e) {
      int d = dst[i];
      int s = src[i];
      int b = d >> BSHIFT;
      bk[k] = b;
      pk[k] = s | ((d & (BNODES - 1)) << 17);
      rk[k] = atomicAdd(&hist[b], 1);
    } else {
      bk[k] = -1;
    }
  }
  __syncthreads();
  int h = hist[tid];
  if (h > 0) gb[tid] = atomicAdd(&cursor[tid], h);
  __syncthreads();
#pragma unroll
  for (int k = 0; k < 16; ++k) {
    if (bk[k] >= 0) binned[bk[k] * CAP + gb[bk[k]] + rk[k]] = pk[k];
  }
}

// ---------------------------------------------------------------- phase 2: scan bucket counts
__global__ __launch_bounds__(256) void k_bucket_scan(const int* __restrict__ cursor,
    int* __restrict__ csrBase, int* __restrict__ offs, int nb, int n, int e) {
  __shared__ int buf[2][256];
  const int tid = threadIdx.x;
  int v = (tid < nb) ? cursor[tid] : 0;
  buf[0][tid] = v;
  __syncthreads();
  int cur = 0;
  for (int d = 1; d < 256; d <<= 1) {
    int t = buf[cur][tid];
    if (tid >= d) t += buf[cur][tid - d];
    buf[cur ^ 1][tid] = t;
    cur ^= 1;
    __syncthreads();
  }
  if (tid < nb) csrBase[tid] = (tid == 0) ? 0 : buf[cur][tid - 1];
  if (tid == 0) {
    csrBase[nb] = e;
    offs[n] = e;
  }
}

// ---------------------------------------------------------------- phase 3: per-bucket CSR build (one wg owns one bucket)
__global__ __launch_bounds__(256) void k_build(const int* __restrict__ binned,
    const int* __restrict__ csrBase, int* __restrict__ offs,
    int* __restrict__ csr, int n) {
  __shared__ int deg[BNODES];
  __shared__ int pre[BNODES];
  __shared__ int wsum[4];
  __shared__ int stage[CAP];
  const int b = blockIdx.x;
  const int tid = threadIdx.x;
  const int nodeBase = b << BSHIFT;
  const int cbase = csrBase[b];
  const int cnt = csrBase[b + 1] - cbase;
  const int* gsrc = binned + b * CAP;

  deg[tid] = 0;
  deg[tid + 256] = 0;
  __syncthreads();
  for (int i = tid; i < cnt; i += 256) atomicAdd(&deg[gsrc[i] >> 17], 1);
  __syncthreads();

  // exclusive scan of deg[512]: 2 elements/thread
  const int lane = tid & 63, w = tid >> 6;
  int a0 = deg[2 * tid], a1 = deg[2 * tid + 1];
  int ps = a0 + a1;
  int s = ps;
#pragma unroll
  for (int d = 1; d < 64; d <<= 1) {
    int t = __shfl_up(s, d, 64);
    if (lane >= d) s += t;
  }
  if (lane == 63) wsum[w] = s;
  __syncthreads();
  if (tid == 0) {
    int acc = 0;
#pragma unroll
    for (int j = 0; j < 4; ++j) { int t = wsum[j]; wsum[j] = acc; acc += t; }
  }
  __syncthreads();
  int ex = wsum[w] + s - ps;
  pre[2 * tid] = ex;
  pre[2 * tid + 1] = ex + a0;
  // reset deg for use as cursor
  deg[tid] = 0;
  deg[tid + 256] = 0;
  __syncthreads();

  const int nNodes = min(BNODES, n - nodeBase);
  for (int i = tid; i < nNodes; i += 256) offs[nodeBase + i] = cbase + pre[i];

  for (int i = tid; i < cnt; i += 256) {
    int v = gsrc[i];
    int dl = v >> 17;
    int p = pre[dl] + atomicAdd(&deg[dl], 1);
    stage[p] = v & 0x1FFFF;
  }
  __syncthreads();
  for (int i = tid; i < cnt; i += 256) csr[cbase + i] = stage[i];
}

// ---------------------------------------------------------------- GEMM1: X(Nx128) @ W1(128x64) -> H(Nx64), no bias
__global__ __launch_bounds__(256) void k_gemm1(
    const float* __restrict__ A, const float* __restrict__ W1,
    float* __restrict__ H, int n) {
  __shared__ float Ws[128 * 64];
  for (int t = threadIdx.x; t < 128 * 64; t += 256) Ws[t] = W1[t];
  __syncthreads();

  const int rg = threadIdx.x >> 4;
  const int c0 = (threadIdx.x & 15) * 4;
  const int row0 = blockIdx.x * 64 + rg * 4;

  float acc[4][4] = {};
  for (int k = 0; k < 128; k += 4) {
    float4 a[4];
#pragma unroll
    for (int r = 0; r < 4; ++r) {
      int row = row0 + r;
      int rowc = row < n ? row : n - 1;
      a[r] = *(const float4*)&A[(size_t)rowc * 128 + k];
    }
    float4 w0 = *(const float4*)&Ws[(k + 0) * 64 + c0];
    float4 w1 = *(const float4*)&Ws[(k + 1) * 64 + c0];
    float4 w2 = *(const float4*)&Ws[(k + 2) * 64 + c0];
    float4 w3 = *(const float4*)&Ws[(k + 3) * 64 + c0];
#pragma unroll
    for (int r = 0; r < 4; ++r) {
      acc[r][0] += a[r].x * w0.x + a[r].y * w1.x + a[r].z * w2.x + a[r].w * w3.x;
      acc[r][1] += a[r].x * w0.y + a[r].y * w1.y + a[r].z * w2.y + a[r].w * w3.y;
      acc[r][2] += a[r].x * w0.z + a[r].y * w1.z + a[r].z * w2.z + a[r].w * w3.z;
      acc[r][3] += a[r].x * w0.w + a[r].y * w1.w + a[r].z * w2.w + a[r].w * w3.w;
    }
  }
#pragma unroll
  for (int r = 0; r < 4; ++r) {
    int row = row0 + r;
    if (row < n) {
      *(float4*)&H[(size_t)row * 64 + c0] =
          make_float4(acc[r][0], acc[r][1], acc[r][2], acc[r][3]);
    }
  }
}

// ---------------------------------------------------------------- hop at D=64: one wave per node (4 edges in flight)
__global__ __launch_bounds__(256) void k_hop64(const float* __restrict__ hin,
    float* __restrict__ hout, const int* __restrict__ offs,
    const int* __restrict__ csr, int n) {
  int wid = (blockIdx.x * 256 + threadIdx.x) >> 6;
  if (wid >= n) return;
  int lane = threadIdx.x & 63;
  int beg = offs[wid], end = offs[wid + 1];
  size_t base = (size_t)wid * 64 + lane;
  float acc = hin[base];
  int e = beg;
  for (; e + 3 < end; e += 4) {
    int j0 = csr[e], j1 = csr[e + 1], j2 = csr[e + 2], j3 = csr[e + 3];
    float v0 = hin[(size_t)j0 * 64 + lane];
    float v1 = hin[(size_t)j1 * 64 + lane];
    float v2 = hin[(size_t)j2 * 64 + lane];
    float v3 = hin[(size_t)j3 * 64 + lane];
    acc += (v0 + v1) + (v2 + v3);
  }
  for (; e < end; ++e) acc += hin[(size_t)csr[e] * 64 + lane];
  hout[base] = acc;
}

// second hop fused with per-column (sum, sumsq) batch stats
// atomics spread over NSLOT copies to bound per-address contention depth
__global__ __launch_bounds__(256) void k_hop64_stats(const float* __restrict__ hin,
    float* __restrict__ hout, const int* __restrict__ offs,
    const int* __restrict__ csr, float* __restrict__ stats, int n) {
  int wid = (blockIdx.x * 256 + threadIdx.x) >> 6;
  int lane = threadIdx.x & 63;
  float acc = 0.f;
  if (wid < n) {
    int beg = offs[wid], end = offs[wid + 1];
    size_t base = (size_t)wid * 64 + lane;
    acc = hin[base];
    int e = beg;
    for (; e + 3 < end; e += 4) {
      int j0 = csr[e], j1 = csr[e + 1], j2 = csr[e + 2], j3 = csr[e + 3];
      float v0 = hin[(size_t)j0 * 64 + lane];
      float v1 = hin[(size_t)j1 * 64 + lane];
      float v2 = hin[(size_t)j2 * 64 + lane];
      float v3 = hin[(size_t)j3 * 64 + lane];
      acc += (v0 + v1) + (v2 + v3);
    }
    for (; e < end; ++e) acc += hin[(size_t)csr[e] * 64 + lane];
    hout[base] = acc;
  }
  __shared__ float l1[4][64];
  __shared__ float l2[4][64];
  const int w = threadIdx.x >> 6;
  float v = (wid < n) ? acc : 0.f;
  l1[w][lane] = v;
  l2[w][lane] = v * v;
  __syncthreads();
  if (threadIdx.x < 64) {
    float t1 = l1[0][lane] + l1[1][lane] + l1[2][lane] + l1[3][lane];
    float t2 = l2[0][lane] + l2[1][lane] + l2[2][lane] + l2[3][lane];
    float* slot = stats + (size_t)(blockIdx.x & (NSLOT - 1)) * 128;
    atomicAdd(&slot[lane], t1);
    atomicAdd(&slot[64 + lane], t2);
  }
}

__global__ void k_finalize_stats(const float* __restrict__ stats,
    const float* __restrict__ bn_w, const float* __restrict__ bn_b,
    float* __restrict__ ab, int n) {
  int f = threadIdx.x;
  if (f < 64) {
    float s1 = 0.f, s2 = 0.f;
#pragma unroll 4
    for (int j = 0; j < NSLOT; ++j) {
      s1 += stats[(size_t)j * 128 + f];
      s2 += stats[(size_t)j * 128 + 64 + f];
    }
    float inv_n = 1.0f / (float)n;
    float mu = s1 * inv_n;
    float var = s2 * inv_n - mu * mu;
    float s = bn_w[f] * rsqrtf(var + 1e-5f);
    ab[f] = s;
    ab[64 + f] = bn_b[f] - mu * s;
  }
}

// ---------------------------------------------------------------- GEMM2 with fused BN affine + SELU
__global__ __launch_bounds__(256) void k_gemm2(const float* __restrict__ A,
    const float* __restrict__ ab, const float* __restrict__ W2,
    float* __restrict__ Y, int n) {
  int row = blockIdx.x * 256 + threadIdx.x;
  if (row >= n) return;
  float4 acc[4] = {make_float4(0, 0, 0, 0), make_float4(0, 0, 0, 0),
                   make_float4(0, 0, 0, 0), make_float4(0, 0, 0, 0)};
  const float4* A4 = (const float4*)(A + (size_t)row * 64);
#pragma unroll
  for (int k = 0; k < 64; k += 4) {
    float4 a = A4[k >> 2];
    float av[4] = {a.x, a.y, a.z, a.w};
#pragma unroll
    for (int kk = 0; kk < 4; ++kk) {
      float y = ab[k + kk] * av[kk] + ab[64 + k + kk];
      y = y > 0.f ? SELU_LAMBDA * y : SELU_LAMBDA * SELU_ALPHA * expm1f(y);
      const float4* Wr = (const float4*)&W2[(k + kk) * 16];
      float4 w0 = Wr[0], w1 = Wr[1], w2 = Wr[2], w3 = Wr[3];
      acc[0].x += y * w0.x; acc[0].y += y * w0.y; acc[0].z += y * w0.z; acc[0].w += y * w0.w;
      acc[1].x += y * w1.x; acc[1].y += y * w1.y; acc[1].z += y * w1.z; acc[1].w += y * w1.w;
      acc[2].x += y * w2.x; acc[2].y += y * w2.y; acc[2].z += y * w2.z; acc[2].w += y * w2.w;
      acc[3].x += y * w3.x; acc[3].y += y * w3.y; acc[3].z += y * w3.z; acc[3].w += y * w3.w;
    }
  }
  float4* o = (float4*)(Y + (size_t)row * 16);
  o[0] = acc[0]; o[1] = acc[1]; o[2] = acc[2]; o[3] = acc[3];
}

// ---------------------------------------------------------------- hop at D=16 + b2 + log_softmax
__global__ __launch_bounds__(256) void k_hop16(const float* __restrict__ Y,
    const float* __restrict__ b2, float* __restrict__ out,
    const int* __restrict__ offs, const int* __restrict__ csr, int n) {
  int wid = (blockIdx.x * 256 + threadIdx.x) >> 6;
  if (wid >= n) return;
  int lane = threadIdx.x & 63;
  int sub = lane >> 4, dim = lane & 15;
  int beg = offs[wid], end = offs[wid + 1];
  float acc = 0.f;
  for (int e = beg; e < end; e += 8) {
    int i0 = e + sub, i1 = e + 4 + sub;
    float v0 = 0.f, v1 = 0.f;
    if (i0 < end) v0 = Y[(size_t)csr[i0] * 16 + dim];
    if (i1 < end) v1 = Y[(size_t)csr[i1] * 16 + dim];
    acc += v0 + v1;
  }
  acc += __shfl_down(acc, 32, 64);
  acc += __shfl_down(acc, 16, 64);
  float v = acc + Y[(size_t)wid * 16 + dim] + b2[dim];
  float m = v;
#pragma unroll
  for (int d = 8; d >= 1; d >>= 1) m = fmaxf(m, __shfl_xor(m, d, 16));
  float s = expf(v - m);
#pragma unroll
  for (int d = 8; d >= 1; d >>= 1) s += __shfl_xor(s, d, 16);
  float r = v - (m + logf(s));
  if (lane < 16) out[(size_t)wid * 16 + dim] = r;
}

// ---------------------------------------------------------------- launch
extern "C" void kernel_launch(void* const* d_in, const int* in_sizes, int n_in,
                              void* d_out, int out_size, void* d_ws, size_t ws_size,
                              hipStream_t stream) {
  const float* x   = (const float*)d_in[0];
  const int* esrc  = (const int*)d_in[1];
  const int* edst  = (const int*)d_in[2];
  const float* W1  = (const float*)d_in[3];
  // d_in[4] = b1: cancels exactly under batchnorm mean subtraction
  const float* bnw = (const float*)d_in[5];
  const float* bnb = (const float*)d_in[6];
  const float* W2  = (const float*)d_in[7];
  const float* b2  = (const float*)d_in[8];
  float* out = (float*)d_out;

  const int N = in_sizes[0] / 128;  // 100000
  const int E = in_sizes[1];        // 1600000
  const int NB = (N + BNODES - 1) >> BSHIFT;  // 196 buckets

  char* p = (char*)d_ws;
  auto alloc = [&](size_t bytes) {
    char* q = p;
    p += (bytes + 255) & ~(size_t)255;
    return q;
  };
  int* cursor  = (int*)alloc(256 * sizeof(int));
  int* csrBase = (int*)alloc(257 * sizeof(int));
  int* binned  = (int*)alloc((size_t)NB * CAP * sizeof(int));
  int* offs    = (int*)alloc((size_t)(N + 4) * sizeof(int));
  int* csr     = (int*)alloc((size_t)E * sizeof(int));
  float* stats = (float*)alloc((size_t)NSLOT * 128 * sizeof(float));
  float* ab    = (float*)alloc(128 * sizeof(float));
  float* bufA  = (float*)alloc((size_t)N * 64 * sizeof(float));
  float* bufB  = (float*)alloc((size_t)N * 64 * sizeof(float));
  float* bufC  = (float*)alloc((size_t)N * 16 * sizeof(float));

  hipMemsetAsync(cursor, 0, 256 * sizeof(int), stream);
  hipMemsetAsync(stats, 0, (size_t)NSLOT * 128 * sizeof(float), stream);

  // CSR build: bin -> scan -> per-bucket build
  k_bin<<<(E + CHUNK - 1) / CHUNK, 256, 0, stream>>>(esrc, edst, cursor, binned, E);
  k_bucket_scan<<<1, 256, 0, stream>>>(cursor, csrBase, offs, NB, N, E);
  k_build<<<NB, 256, 0, stream>>>(binned, csrBase, offs, csr, N);

  // GEMM first (propagation commutes with the linear layer): hops run at D=64
  k_gemm1<<<(N + 63) / 64, 256, 0, stream>>>(x, W1, bufA, N);

  int hopBlocks = (N * 64 + 255) / 256;  // one wave per node
  k_hop64<<<hopBlocks, 256, 0, stream>>>(bufA, bufB, offs, csr, N);
  k_hop64_stats<<<hopBlocks, 256, 0, stream>>>(bufB, bufA, offs, csr, stats, N);

  k_finalize_stats<<<1, 64, 0, stream>>>(stats, bnw, bnb, ab, N);

  // GEMM2 (with fused BN+SELU) before the last hop: hop runs at D=16
  k_gemm2<<<(N + 255) / 256, 256, 0, stream>>>(bufA, ab, W2, bufC, N);
  k_hop16<<<hopBlocks, 256, 0, stream>>>(bufC, b2, out, offs, csr, N);
}

// Round 5
// 280.634 us; speedup vs baseline: 3.0463x; 1.1368x over previous
//
#include <hip/hip_runtime.h>
#include <math.h>

#define SELU_LAMBDA 1.0507009873554805f
#define SELU_ALPHA  1.6732632423543772f

#define BSHIFT 9
#define BNODES 512          // nodes per bucket
#define CAP    10240        // bucket capacity (mean 8192, +22 sigma)
#define CHUNK  4096         // edges per k_bin block
#define NSLOT  64           // stats atomic spreading slots

// bf16 helpers (round-to-nearest-even via bias trick; inputs are finite)
__device__ __forceinline__ unsigned short f2bf(float f) {
  unsigned int u = __float_as_uint(f);
  u += 0x7FFF + ((u >> 16) & 1);
  return (unsigned short)(u >> 16);
}
__device__ __forceinline__ float bf2f(unsigned short u) {
  return __uint_as_float(((unsigned int)u) << 16);
}

// ---------------------------------------------------------------- phase 1: bin edges by dst bucket
// packed entry: src | (dstLocal << 17)   (src < 2^17, dstLocal < 2^9)
__global__ __launch_bounds__(256) void k_bin(const int* __restrict__ src,
    const int* __restrict__ dst, int* __restrict__ cursor,
    int* __restrict__ binned, int e) {
  __shared__ int hist[256];
  __shared__ int gb[256];
  const int tid = threadIdx.x;
  hist[tid] = 0;
  __syncthreads();
  const int base = blockIdx.x * CHUNK;
  int bk[16], rk[16], pk[16];
#pragma unroll
  for (int k = 0; k < 16; ++k) {
    int i = base + k * 256 + tid;
    if (i < e) {
      int d = dst[i];
      int s = src[i];
      int b = d >> BSHIFT;
      bk[k] = b;
      pk[k] = s | ((d & (BNODES - 1)) << 17);
      rk[k] = atomicAdd(&hist[b], 1);
    } else {
      bk[k] = -1;
    }
  }
  __syncthreads();
  int h = hist[tid];
  if (h > 0) gb[tid] = atomicAdd(&cursor[tid], h);
  __syncthreads();
#pragma unroll
  for (int k = 0; k < 16; ++k) {
    if (bk[k] >= 0) binned[bk[k] * CAP + gb[bk[k]] + rk[k]] = pk[k];
  }
}

// ---------------------------------------------------------------- phase 2: scan bucket counts
__global__ __launch_bounds__(256) void k_bucket_scan(const int* __restrict__ cursor,
    int* __restrict__ csrBase, int* __restrict__ offs, int nb, int n, int e) {
  __shared__ int buf[2][256];
  const int tid = threadIdx.x;
  int v = (tid < nb) ? cursor[tid] : 0;
  buf[0][tid] = v;
  __syncthreads();
  int cur = 0;
  for (int d = 1; d < 256; d <<= 1) {
    int t = buf[cur][tid];
    if (tid >= d) t += buf[cur][tid - d];
    buf[cur ^ 1][tid] = t;
    cur ^= 1;
    __syncthreads();
  }
  if (tid < nb) csrBase[tid] = (tid == 0) ? 0 : buf[cur][tid - 1];
  if (tid == 0) {
    csrBase[nb] = e;
    offs[n] = e;
  }
}

// ---------------------------------------------------------------- phase 3: per-bucket CSR build (one wg owns one bucket)
__global__ __launch_bounds__(256) void k_build(const int* __restrict__ binned,
    const int* __restrict__ csrBase, int* __restrict__ offs,
    int* __restrict__ csr, int n) {
  __shared__ int deg[BNODES];
  __shared__ int pre[BNODES];
  __shared__ int wsum[4];
  __shared__ int stage[CAP];
  const int b = blockIdx.x;
  const int tid = threadIdx.x;
  const int nodeBase = b << BSHIFT;
  const int cbase = csrBase[b];
  const int cnt = csrBase[b + 1] - cbase;
  const int* gsrc = binned + b * CAP;

  deg[tid] = 0;
  deg[tid + 256] = 0;
  __syncthreads();
  for (int i = tid; i < cnt; i += 256) atomicAdd(&deg[gsrc[i] >> 17], 1);
  __syncthreads();

  // exclusive scan of deg[512]: 2 elements/thread
  const int lane = tid & 63, w = tid >> 6;
  int a0 = deg[2 * tid], a1 = deg[2 * tid + 1];
  int ps = a0 + a1;
  int s = ps;
#pragma unroll
  for (int d = 1; d < 64; d <<= 1) {
    int t = __shfl_up(s, d, 64);
    if (lane >= d) s += t;
  }
  if (lane == 63) wsum[w] = s;
  __syncthreads();
  if (tid == 0) {
    int acc = 0;
#pragma unroll
    for (int j = 0; j < 4; ++j) { int t = wsum[j]; wsum[j] = acc; acc += t; }
  }
  __syncthreads();
  int ex = wsum[w] + s - ps;
  pre[2 * tid] = ex;
  pre[2 * tid + 1] = ex + a0;
  // reset deg for use as cursor
  deg[tid] = 0;
  deg[tid + 256] = 0;
  __syncthreads();

  const int nNodes = min(BNODES, n - nodeBase);
  for (int i = tid; i < nNodes; i += 256) offs[nodeBase + i] = cbase + pre[i];

  for (int i = tid; i < cnt; i += 256) {
    int v = gsrc[i];
    int dl = v >> 17;
    int p = pre[dl] + atomicAdd(&deg[dl], 1);
    stage[p] = v & 0x1FFFF;
  }
  __syncthreads();
  for (int i = tid; i < cnt; i += 256) csr[cbase + i] = stage[i];
}

// ---------------------------------------------------------------- GEMM1: X(Nx128) @ W1(128x64) -> H1(Nx64) in bf16
__global__ __launch_bounds__(256) void k_gemm1(
    const float* __restrict__ A, const float* __restrict__ W1,
    unsigned short* __restrict__ H, int n) {
  __shared__ float Ws[128 * 64];
  for (int t = threadIdx.x; t < 128 * 64; t += 256) Ws[t] = W1[t];
  __syncthreads();

  const int rg = threadIdx.x >> 4;
  const int c0 = (threadIdx.x & 15) * 4;
  const int row0 = blockIdx.x * 64 + rg * 4;

  float acc[4][4] = {};
  for (int k = 0; k < 128; k += 4) {
    float4 a[4];
#pragma unroll
    for (int r = 0; r < 4; ++r) {
      int row = row0 + r;
      int rowc = row < n ? row : n - 1;
      a[r] = *(const float4*)&A[(size_t)rowc * 128 + k];
    }
    float4 w0 = *(const float4*)&Ws[(k + 0) * 64 + c0];
    float4 w1 = *(const float4*)&Ws[(k + 1) * 64 + c0];
    float4 w2 = *(const float4*)&Ws[(k + 2) * 64 + c0];
    float4 w3 = *(const float4*)&Ws[(k + 3) * 64 + c0];
#pragma unroll
    for (int r = 0; r < 4; ++r) {
      acc[r][0] += a[r].x * w0.x + a[r].y * w1.x + a[r].z * w2.x + a[r].w * w3.x;
      acc[r][1] += a[r].x * w0.y + a[r].y * w1.y + a[r].z * w2.y + a[r].w * w3.y;
      acc[r][2] += a[r].x * w0.z + a[r].y * w1.z + a[r].z * w2.z + a[r].w * w3.z;
      acc[r][3] += a[r].x * w0.w + a[r].y * w1.w + a[r].z * w2.w + a[r].w * w3.w;
    }
  }
#pragma unroll
  for (int r = 0; r < 4; ++r) {
    int row = row0 + r;
    if (row < n) {
      ushort4 o;
      o.x = f2bf(acc[r][0]); o.y = f2bf(acc[r][1]);
      o.z = f2bf(acc[r][2]); o.w = f2bf(acc[r][3]);
      *(ushort4*)&H[(size_t)row * 64 + c0] = o;
    }
  }
}

// ---------------------------------------------------------------- hop1 at D=64 (bf16 in, bf16 out): one wave per node
__global__ __launch_bounds__(256) void k_hop64b(const unsigned short* __restrict__ hin,
    unsigned short* __restrict__ hout, const int* __restrict__ offs,
    const int* __restrict__ csr, int n) {
  int wid = (blockIdx.x * 256 + threadIdx.x) >> 6;
  if (wid >= n) return;
  int lane = threadIdx.x & 63;
  int beg = offs[wid], end = offs[wid + 1];
  size_t base = (size_t)wid * 64 + lane;
  float acc = bf2f(hin[base]);
  int e = beg;
  for (; e + 7 < end; e += 8) {
    float v0 = bf2f(hin[(size_t)csr[e + 0] * 64 + lane]);
    float v1 = bf2f(hin[(size_t)csr[e + 1] * 64 + lane]);
    float v2 = bf2f(hin[(size_t)csr[e + 2] * 64 + lane]);
    float v3 = bf2f(hin[(size_t)csr[e + 3] * 64 + lane]);
    float v4 = bf2f(hin[(size_t)csr[e + 4] * 64 + lane]);
    float v5 = bf2f(hin[(size_t)csr[e + 5] * 64 + lane]);
    float v6 = bf2f(hin[(size_t)csr[e + 6] * 64 + lane]);
    float v7 = bf2f(hin[(size_t)csr[e + 7] * 64 + lane]);
    acc += ((v0 + v1) + (v2 + v3)) + ((v4 + v5) + (v6 + v7));
  }
  for (; e + 1 < end; e += 2) {
    float v0 = bf2f(hin[(size_t)csr[e] * 64 + lane]);
    float v1 = bf2f(hin[(size_t)csr[e + 1] * 64 + lane]);
    acc += v0 + v1;
  }
  if (e < end) acc += bf2f(hin[(size_t)csr[e] * 64 + lane]);
  hout[base] = f2bf(acc);
}

// hop2 at D=64 (bf16 in, fp32 out) fused with per-column (sum, sumsq) batch stats
__global__ __launch_bounds__(256) void k_hop64b_stats(const unsigned short* __restrict__ hin,
    float* __restrict__ hout, const int* __restrict__ offs,
    const int* __restrict__ csr, float* __restrict__ stats, int n) {
  int wid = (blockIdx.x * 256 + threadIdx.x) >> 6;
  int lane = threadIdx.x & 63;
  float acc = 0.f;
  if (wid < n) {
    int beg = offs[wid], end = offs[wid + 1];
    size_t base = (size_t)wid * 64 + lane;
    acc = bf2f(hin[base]);
    int e = beg;
    for (; e + 7 < end; e += 8) {
      float v0 = bf2f(hin[(size_t)csr[e + 0] * 64 + lane]);
      float v1 = bf2f(hin[(size_t)csr[e + 1] * 64 + lane]);
      float v2 = bf2f(hin[(size_t)csr[e + 2] * 64 + lane]);
      float v3 = bf2f(hin[(size_t)csr[e + 3] * 64 + lane]);
      float v4 = bf2f(hin[(size_t)csr[e + 4] * 64 + lane]);
      float v5 = bf2f(hin[(size_t)csr[e + 5] * 64 + lane]);
      float v6 = bf2f(hin[(size_t)csr[e + 6] * 64 + lane]);
      float v7 = bf2f(hin[(size_t)csr[e + 7] * 64 + lane]);
      acc += ((v0 + v1) + (v2 + v3)) + ((v4 + v5) + (v6 + v7));
    }
    for (; e + 1 < end; e += 2) {
      float v0 = bf2f(hin[(size_t)csr[e] * 64 + lane]);
      float v1 = bf2f(hin[(size_t)csr[e + 1] * 64 + lane]);
      acc += v0 + v1;
    }
    if (e < end) acc += bf2f(hin[(size_t)csr[e] * 64 + lane]);
    hout[(size_t)wid * 64 + lane] = acc;
  }
  __shared__ float l1[4][64];
  __shared__ float l2[4][64];
  const int w = threadIdx.x >> 6;
  float v = (wid < n) ? acc : 0.f;
  l1[w][lane] = v;
  l2[w][lane] = v * v;
  __syncthreads();
  if (threadIdx.x < 64) {
    float t1 = l1[0][lane] + l1[1][lane] + l1[2][lane] + l1[3][lane];
    float t2 = l2[0][lane] + l2[1][lane] + l2[2][lane] + l2[3][lane];
    float* slot = stats + (size_t)(blockIdx.x & (NSLOT - 1)) * 128;
    atomicAdd(&slot[lane], t1);
    atomicAdd(&slot[64 + lane], t2);
  }
}

__global__ void k_finalize_stats(const float* __restrict__ stats,
    const float* __restrict__ bn_w, const float* __restrict__ bn_b,
    float* __restrict__ ab, int n) {
  int f = threadIdx.x;
  if (f < 64) {
    float s1 = 0.f, s2 = 0.f;
#pragma unroll 4
    for (int j = 0; j < NSLOT; ++j) {
      s1 += stats[(size_t)j * 128 + f];
      s2 += stats[(size_t)j * 128 + 64 + f];
    }
    float inv_n = 1.0f / (float)n;
    float mu = s1 * inv_n;
    float var = s2 * inv_n - mu * mu;
    float s = bn_w[f] * rsqrtf(var + 1e-5f);
    ab[f] = s;
    ab[64 + f] = bn_b[f] - mu * s;
  }
}

// ---------------------------------------------------------------- GEMM2 with fused BN affine + SELU -> Y bf16 (Nx16)
__global__ __launch_bounds__(256) void k_gemm2(const float* __restrict__ A,
    const float* __restrict__ ab, const float* __restrict__ W2,
    unsigned short* __restrict__ Y, int n) {
  int row = blockIdx.x * 256 + threadIdx.x;
  if (row >= n) return;
  float4 acc[4] = {make_float4(0, 0, 0, 0), make_float4(0, 0, 0, 0),
                   make_float4(0, 0, 0, 0), make_float4(0, 0, 0, 0)};
  const float4* A4 = (const float4*)(A + (size_t)row * 64);
#pragma unroll
  for (int k = 0; k < 64; k += 4) {
    float4 a = A4[k >> 2];
    float av[4] = {a.x, a.y, a.z, a.w};
#pragma unroll
    for (int kk = 0; kk < 4; ++kk) {
      float y = ab[k + kk] * av[kk] + ab[64 + k + kk];
      y = y > 0.f ? SELU_LAMBDA * y : SELU_LAMBDA * SELU_ALPHA * expm1f(y);
      const float4* Wr = (const float4*)&W2[(k + kk) * 16];
      float4 w0 = Wr[0], w1 = Wr[1], w2 = Wr[2], w3 = Wr[3];
      acc[0].x += y * w0.x; acc[0].y += y * w0.y; acc[0].z += y * w0.z; acc[0].w += y * w0.w;
      acc[1].x += y * w1.x; acc[1].y += y * w1.y; acc[1].z += y * w1.z; acc[1].w += y * w1.w;
      acc[2].x += y * w2.x; acc[2].y += y * w2.y; acc[2].z += y * w2.z; acc[2].w += y * w2.w;
      acc[3].x += y * w3.x; acc[3].y += y * w3.y; acc[3].z += y * w3.z; acc[3].w += y * w3.w;
    }
  }
  ushort4 o0, o1, o2, o3;
  o0.x = f2bf(acc[0].x); o0.y = f2bf(acc[0].y); o0.z = f2bf(acc[0].z); o0.w = f2bf(acc[0].w);
  o1.x = f2bf(acc[1].x); o1.y = f2bf(acc[1].y); o1.z = f2bf(acc[1].z); o1.w = f2bf(acc[1].w);
  o2.x = f2bf(acc[2].x); o2.y = f2bf(acc[2].y); o2.z = f2bf(acc[2].z); o2.w = f2bf(acc[2].w);
  o3.x = f2bf(acc[3].x); o3.y = f2bf(acc[3].y); o3.z = f2bf(acc[3].z); o3.w = f2bf(acc[3].w);
  ushort4* o = (ushort4*)(Y + (size_t)row * 16);
  o[0] = o0; o[1] = o1; o[2] = o2; o[3] = o3;
}

// ---------------------------------------------------------------- hop at D=16 (bf16 in) + b2 + log_softmax
__global__ __launch_bounds__(256) void k_hop16(const unsigned short* __restrict__ Y,
    const float* __restrict__ b2, float* __restrict__ out,
    const int* __restrict__ offs, const int* __restrict__ csr, int n) {
  int wid = (blockIdx.x * 256 + threadIdx.x) >> 6;
  if (wid >= n) return;
  int lane = threadIdx.x & 63;
  int sub = lane >> 4, dim = lane & 15;
  int beg = offs[wid], end = offs[wid + 1];
  float acc = 0.f;
  for (int e = beg; e < end; e += 8) {
    int i0 = e + sub, i1 = e + 4 + sub;
    float v0 = 0.f, v1 = 0.f;
    if (i0 < end) v0 = bf2f(Y[(size_t)csr[i0] * 16 + dim]);
    if (i1 < end) v1 = bf2f(Y[(size_t)csr[i1] * 16 + dim]);
    acc += v0 + v1;
  }
  acc += __shfl_down(acc, 32, 64);
  acc += __shfl_down(acc, 16, 64);
  float v = acc + bf2f(Y[(size_t)wid * 16 + dim]) + b2[dim];
  float m = v;
#pragma unroll
  for (int d = 8; d >= 1; d >>= 1) m = fmaxf(m, __shfl_xor(m, d, 16));
  float s = expf(v - m);
#pragma unroll
  for (int d = 8; d >= 1; d >>= 1) s += __shfl_xor(s, d, 16);
  float r = v - (m + logf(s));
  if (lane < 16) out[(size_t)wid * 16 + dim] = r;
}

// ---------------------------------------------------------------- launch
extern "C" void kernel_launch(void* const* d_in, const int* in_sizes, int n_in,
                              void* d_out, int out_size, void* d_ws, size_t ws_size,
                              hipStream_t stream) {
  const float* x   = (const float*)d_in[0];
  const int* esrc  = (const int*)d_in[1];
  const int* edst  = (const int*)d_in[2];
  const float* W1  = (const float*)d_in[3];
  // d_in[4] = b1: cancels exactly under batchnorm mean subtraction
  const float* bnw = (const float*)d_in[5];
  const float* bnb = (const float*)d_in[6];
  const float* W2  = (const float*)d_in[7];
  const float* b2  = (const float*)d_in[8];
  float* out = (float*)d_out;

  const int N = in_sizes[0] / 128;  // 100000
  const int E = in_sizes[1];        // 1600000
  const int NB = (N + BNODES - 1) >> BSHIFT;  // 196 buckets

  char* p = (char*)d_ws;
  auto alloc = [&](size_t bytes) {
    char* q = p;
    p += (bytes + 255) & ~(size_t)255;
    return q;
  };
  int* cursor  = (int*)alloc(256 * sizeof(int));
  int* csrBase = (int*)alloc(257 * sizeof(int));
  int* binned  = (int*)alloc((size_t)NB * CAP * sizeof(int));
  int* offs    = (int*)alloc((size_t)(N + 4) * sizeof(int));
  int* csr     = (int*)alloc((size_t)E * sizeof(int));
  float* stats = (float*)alloc((size_t)NSLOT * 128 * sizeof(float));
  float* ab    = (float*)alloc(128 * sizeof(float));
  unsigned short* h1 = (unsigned short*)alloc((size_t)N * 64 * sizeof(unsigned short));
  unsigned short* h2 = (unsigned short*)alloc((size_t)N * 64 * sizeof(unsigned short));
  float* bufA  = (float*)alloc((size_t)N * 64 * sizeof(float));
  unsigned short* Yb = (unsigned short*)alloc((size_t)N * 16 * sizeof(unsigned short));

  hipMemsetAsync(cursor, 0, 256 * sizeof(int), stream);
  hipMemsetAsync(stats, 0, (size_t)NSLOT * 128 * sizeof(float), stream);

  // CSR build: bin -> scan -> per-bucket build
  k_bin<<<(E + CHUNK - 1) / CHUNK, 256, 0, stream>>>(esrc, edst, cursor, binned, E);
  k_bucket_scan<<<1, 256, 0, stream>>>(cursor, csrBase, offs, NB, N, E);
  k_build<<<NB, 256, 0, stream>>>(binned, csrBase, offs, csr, N);

  // GEMM first (propagation commutes with the linear layer): hops run at D=64 bf16
  k_gemm1<<<(N + 63) / 64, 256, 0, stream>>>(x, W1, h1, N);

  int hopBlocks = (N * 64 + 255) / 256;  // one wave per node
  k_hop64b<<<hopBlocks, 256, 0, stream>>>(h1, h2, offs, csr, N);
  k_hop64b_stats<<<hopBlocks, 256, 0, stream>>>(h2, bufA, offs, csr, stats, N);

  k_finalize_stats<<<1, 64, 0, stream>>>(stats, bnw, bnb, ab, N);

  // GEMM2 (with fused BN+SELU) before the last hop: hop runs at D=16 bf16
  k_gemm2<<<(N + 255) / 256, 256, 0, stream>>>(bufA, ab, W2, Yb, N);
  k_hop16<<<hopBlocks, 256, 0, stream>>>(Yb, b2, out, offs, csr, N);
}

// Round 6
// 264.282 us; speedup vs baseline: 3.2348x; 1.0619x over previous
//
#include <hip/hip_runtime.h>
#include <math.h>

#define SELU_LAMBDA 1.0507009873554805f
#define SELU_ALPHA  1.6732632423543772f

#define BSHIFT 9
#define BNODES 512          // nodes per bucket
#define CAP    10240        // bucket capacity (mean 8192, +22 sigma)
#define CHUNK  4096         // edges per k_bin block
#define NSLOT  64           // stats atomic spreading slots

// bf16 helpers (round-to-nearest-even via bias trick; inputs are finite)
__device__ __forceinline__ unsigned short f2bf(float f) {
  unsigned int u = __float_as_uint(f);
  u += 0x7FFF + ((u >> 16) & 1);
  return (unsigned short)(u >> 16);
}
__device__ __forceinline__ float bf2f(unsigned short u) {
  return __uint_as_float(((unsigned int)u) << 16);
}

// ---------------------------------------------------------------- phase 1: bin edges by dst bucket
// packed entry: src | (dstLocal << 17)   (src < 2^17, dstLocal < 2^9)
__global__ __launch_bounds__(256) void k_bin(const int* __restrict__ src,
    const int* __restrict__ dst, int* __restrict__ cursor,
    int* __restrict__ binned, int e) {
  __shared__ int hist[256];
  __shared__ int gb[256];
  const int tid = threadIdx.x;
  hist[tid] = 0;
  __syncthreads();
  const int base = blockIdx.x * CHUNK;
  int bk[16], rk[16], pk[16];
#pragma unroll
  for (int k = 0; k < 16; ++k) {
    int i = base + k * 256 + tid;
    if (i < e) {
      int d = dst[i];
      int s = src[i];
      int b = d >> BSHIFT;
      bk[k] = b;
      pk[k] = s | ((d & (BNODES - 1)) << 17);
      rk[k] = atomicAdd(&hist[b], 1);
    } else {
      bk[k] = -1;
    }
  }
  __syncthreads();
  int h = hist[tid];
  if (h > 0) gb[tid] = atomicAdd(&cursor[tid], h);
  __syncthreads();
#pragma unroll
  for (int k = 0; k < 16; ++k) {
    if (bk[k] >= 0) binned[bk[k] * CAP + gb[bk[k]] + rk[k]] = pk[k];
  }
}

// ---------------------------------------------------------------- phase 2: per-bucket CSR build (one wg owns one bucket)
// bucket-count scan replicated per block (196 entries, trivial)
__global__ __launch_bounds__(256) void k_build(const int* __restrict__ binned,
    const int* __restrict__ cursor, int* __restrict__ offs,
    int* __restrict__ csr, int n, int nb, int etot) {
  __shared__ int sc[2][256];
  __shared__ int deg[BNODES];
  __shared__ int pre[BNODES];
  __shared__ int wsum[4];
  __shared__ int stage[CAP];
  __shared__ int s_cbase;
  const int b = blockIdx.x;
  const int tid = threadIdx.x;

  // replicated inclusive scan of the nb bucket counts
  int v0 = (tid < nb) ? cursor[tid] : 0;
  sc[0][tid] = v0;
  __syncthreads();
  int cur = 0;
  for (int d = 1; d < 256; d <<= 1) {
    int t = sc[cur][tid];
    if (tid >= d) t += sc[cur][tid - d];
    sc[cur ^ 1][tid] = t;
    cur ^= 1;
    __syncthreads();
  }
  if (tid == 0) {
    s_cbase = (b == 0) ? 0 : sc[cur][b - 1];
    if (b == 0) offs[n] = etot;
  }
  deg[tid] = 0;
  deg[tid + 256] = 0;
  __syncthreads();
  const int cbase = s_cbase;
  const int cnt = sc[cur][b] - cbase;

  const int nodeBase = b << BSHIFT;
  const int* gsrc = binned + b * CAP;

  for (int i = tid; i < cnt; i += 256) atomicAdd(&deg[gsrc[i] >> 17], 1);
  __syncthreads();

  // exclusive scan of deg[512]: 2 elements/thread
  const int lane = tid & 63, w = tid >> 6;
  int a0 = deg[2 * tid], a1 = deg[2 * tid + 1];
  int ps = a0 + a1;
  int s = ps;
#pragma unroll
  for (int d = 1; d < 64; d <<= 1) {
    int t = __shfl_up(s, d, 64);
    if (lane >= d) s += t;
  }
  if (lane == 63) wsum[w] = s;
  __syncthreads();
  if (tid == 0) {
    int acc = 0;
#pragma unroll
    for (int j = 0; j < 4; ++j) { int t = wsum[j]; wsum[j] = acc; acc += t; }
  }
  __syncthreads();
  int ex = wsum[w] + s - ps;
  pre[2 * tid] = ex;
  pre[2 * tid + 1] = ex + a0;
  // reset deg for use as cursor
  deg[tid] = 0;
  deg[tid + 256] = 0;
  __syncthreads();

  const int nNodes = min(BNODES, n - nodeBase);
  for (int i = tid; i < nNodes; i += 256) offs[nodeBase + i] = cbase + pre[i];

  for (int i = tid; i < cnt; i += 256) {
    int v = gsrc[i];
    int dl = v >> 17;
    int p = pre[dl] + atomicAdd(&deg[dl], 1);
    stage[p] = v & 0x1FFFF;
  }
  __syncthreads();
  for (int i = tid; i < cnt; i += 256) csr[cbase + i] = stage[i];
}

// ---------------------------------------------------------------- GEMM1: X(Nx128) @ W1(128x64) -> H1(Nx64) in bf16
__global__ __launch_bounds__(256) void k_gemm1(
    const float* __restrict__ A, const float* __restrict__ W1,
    unsigned short* __restrict__ H, int n) {
  __shared__ float Ws[128 * 64];
  for (int t = threadIdx.x; t < 128 * 64; t += 256) Ws[t] = W1[t];
  __syncthreads();

  const int rg = threadIdx.x >> 4;
  const int c0 = (threadIdx.x & 15) * 4;
  const int row0 = blockIdx.x * 64 + rg * 4;

  float acc[4][4] = {};
  for (int k = 0; k < 128; k += 4) {
    float4 a[4];
#pragma unroll
    for (int r = 0; r < 4; ++r) {
      int row = row0 + r;
      int rowc = row < n ? row : n - 1;
      a[r] = *(const float4*)&A[(size_t)rowc * 128 + k];
    }
    float4 w0 = *(const float4*)&Ws[(k + 0) * 64 + c0];
    float4 w1 = *(const float4*)&Ws[(k + 1) * 64 + c0];
    float4 w2 = *(const float4*)&Ws[(k + 2) * 64 + c0];
    float4 w3 = *(const float4*)&Ws[(k + 3) * 64 + c0];
#pragma unroll
    for (int r = 0; r < 4; ++r) {
      acc[r][0] += a[r].x * w0.x + a[r].y * w1.x + a[r].z * w2.x + a[r].w * w3.x;
      acc[r][1] += a[r].x * w0.y + a[r].y * w1.y + a[r].z * w2.y + a[r].w * w3.y;
      acc[r][2] += a[r].x * w0.z + a[r].y * w1.z + a[r].z * w2.z + a[r].w * w3.z;
      acc[r][3] += a[r].x * w0.w + a[r].y * w1.w + a[r].z * w2.w + a[r].w * w3.w;
    }
  }
#pragma unroll
  for (int r = 0; r < 4; ++r) {
    int row = row0 + r;
    if (row < n) {
      ushort4 o;
      o.x = f2bf(acc[r][0]); o.y = f2bf(acc[r][1]);
      o.z = f2bf(acc[r][2]); o.w = f2bf(acc[r][3]);
      *(ushort4*)&H[(size_t)row * 64 + c0] = o;
    }
  }
}

// ---------------------------------------------------------------- hop at D=64 (bf16 in/out): one wave per node
// single predicated 16-batch (avg degree) + predicated 8-batch + scalar tail
__device__ __forceinline__ float hop64_gather(const unsigned short* __restrict__ hin,
    const int* __restrict__ offs, const int* __restrict__ csr,
    int wid, int lane, int ecnt) {
  int beg = offs[wid], end = offs[wid + 1];
  int dg = end - beg;
  size_t base = (size_t)wid * 64 + lane;
  float acc = bf2f(hin[base]);
  // batch 1: 16 gathers, padded with self-row (L1/L2 warm), masked out of sum
  int idx[16];
#pragma unroll
  for (int k = 0; k < 16; ++k) {
    int a = beg + k;
    idx[k] = (a < end) ? csr[min(a, ecnt - 1)] : wid;
  }
  float v[16];
#pragma unroll
  for (int k = 0; k < 16; ++k) v[k] = bf2f(hin[(size_t)idx[k] * 64 + lane]);
  float s = 0.f;
#pragma unroll
  for (int k = 0; k < 16; ++k) s += (k < dg) ? v[k] : 0.f;
  acc += s;
  // batch 2: up to 8 more (P(deg>16) ~ 0.47)
  int e2 = beg + 16;
  if (e2 < end) {
    int d2 = end - e2;
    int jx[8];
#pragma unroll
    for (int k = 0; k < 8; ++k) {
      int a = e2 + k;
      jx[k] = (a < end) ? csr[min(a, ecnt - 1)] : wid;
    }
    float w[8];
#pragma unroll
    for (int k = 0; k < 8; ++k) w[k] = bf2f(hin[(size_t)jx[k] * 64 + lane]);
    float s2 = 0.f;
#pragma unroll
    for (int k = 0; k < 8; ++k) s2 += (k < d2) ? w[k] : 0.f;
    acc += s2;
    for (int ee = e2 + 8; ee < end; ++ee)
      acc += bf2f(hin[(size_t)csr[ee] * 64 + lane]);
  }
  return acc;
}

__global__ __launch_bounds__(256) void k_hop64b(const unsigned short* __restrict__ hin,
    unsigned short* __restrict__ hout, const int* __restrict__ offs,
    const int* __restrict__ csr, int n, int ecnt) {
  int wid = (blockIdx.x * 256 + threadIdx.x) >> 6;
  if (wid >= n) return;
  int lane = threadIdx.x & 63;
  float acc = hop64_gather(hin, offs, csr, wid, lane, ecnt);
  hout[(size_t)wid * 64 + lane] = f2bf(acc);
}

// hop2: bf16 in -> bf16 out, fused per-column (sum, sumsq) batch stats (fp32, pre-rounding)
__global__ __launch_bounds__(256) void k_hop64b_stats(const unsigned short* __restrict__ hin,
    unsigned short* __restrict__ hout, const int* __restrict__ offs,
    const int* __restrict__ csr, float* __restrict__ stats, int n, int ecnt) {
  int wid = (blockIdx.x * 256 + threadIdx.x) >> 6;
  int lane = threadIdx.x & 63;
  float acc = 0.f;
  if (wid < n) {
    acc = hop64_gather(hin, offs, csr, wid, lane, ecnt);
    hout[(size_t)wid * 64 + lane] = f2bf(acc);
  }
  __shared__ float l1[4][64];
  __shared__ float l2[4][64];
  const int w = threadIdx.x >> 6;
  float v = (wid < n) ? acc : 0.f;
  l1[w][lane] = v;
  l2[w][lane] = v * v;
  __syncthreads();
  if (threadIdx.x < 64) {
    float t1 = l1[0][lane] + l1[1][lane] + l1[2][lane] + l1[3][lane];
    float t2 = l2[0][lane] + l2[1][lane] + l2[2][lane] + l2[3][lane];
    float* slot = stats + (size_t)(blockIdx.x & (NSLOT - 1)) * 128;
    atomicAdd(&slot[lane], t1);
    atomicAdd(&slot[64 + lane], t2);
  }
}

__global__ void k_finalize_stats(const float* __restrict__ stats,
    const float* __restrict__ bn_w, const float* __restrict__ bn_b,
    float* __restrict__ ab, int n) {
  int f = threadIdx.x;
  if (f < 64) {
    float s1 = 0.f, s2 = 0.f;
#pragma unroll 4
    for (int j = 0; j < NSLOT; ++j) {
      s1 += stats[(size_t)j * 128 + f];
      s2 += stats[(size_t)j * 128 + 64 + f];
    }
    float inv_n = 1.0f / (float)n;
    float mu = s1 * inv_n;
    float var = s2 * inv_n - mu * mu;
    float s = bn_w[f] * rsqrtf(var + 1e-5f);
    ab[f] = s;
    ab[64 + f] = bn_b[f] - mu * s;
  }
}

// ---------------------------------------------------------------- GEMM2 (bf16 in) with fused BN affine + SELU -> Y bf16 (Nx16)
__global__ __launch_bounds__(256) void k_gemm2(const unsigned short* __restrict__ A,
    const float* __restrict__ ab, const float* __restrict__ W2,
    unsigned short* __restrict__ Y, int n) {
  int row = blockIdx.x * 256 + threadIdx.x;
  if (row >= n) return;
  float4 acc0 = make_float4(0, 0, 0, 0), acc1 = acc0, acc2 = acc0, acc3 = acc0;
  const uint4* A4 = (const uint4*)(A + (size_t)row * 64);
#pragma unroll
  for (int kb = 0; kb < 8; ++kb) {
    uint4 a = A4[kb];
    unsigned int pk[4] = {a.x, a.y, a.z, a.w};
#pragma unroll
    for (int q = 0; q < 8; ++q) {
      int k = kb * 8 + q;
      unsigned int word = pk[q >> 1];
      float f = bf2f((unsigned short)((q & 1) ? (word >> 16) : (word & 0xFFFFu)));
      float y = ab[k] * f + ab[64 + k];
      y = y > 0.f ? SELU_LAMBDA * y : SELU_LAMBDA * SELU_ALPHA * expm1f(y);
      const float4* Wr = (const float4*)&W2[k * 16];
      float4 w0 = Wr[0], w1 = Wr[1], w2 = Wr[2], w3 = Wr[3];
      acc0.x += y * w0.x; acc0.y += y * w0.y; acc0.z += y * w0.z; acc0.w += y * w0.w;
      acc1.x += y * w1.x; acc1.y += y * w1.y; acc1.z += y * w1.z; acc1.w += y * w1.w;
      acc2.x += y * w2.x; acc2.y += y * w2.y; acc2.z += y * w2.z; acc2.w += y * w2.w;
      acc3.x += y * w3.x; acc3.y += y * w3.y; acc3.z += y * w3.z; acc3.w += y * w3.w;
    }
  }
  ushort4 o0, o1, o2, o3;
  o0.x = f2bf(acc0.x); o0.y = f2bf(acc0.y); o0.z = f2bf(acc0.z); o0.w = f2bf(acc0.w);
  o1.x = f2bf(acc1.x); o1.y = f2bf(acc1.y); o1.z = f2bf(acc1.z); o1.w = f2bf(acc1.w);
  o2.x = f2bf(acc2.x); o2.y = f2bf(acc2.y); o2.z = f2bf(acc2.z); o2.w = f2bf(acc2.w);
  o3.x = f2bf(acc3.x); o3.y = f2bf(acc3.y); o3.z = f2bf(acc3.z); o3.w = f2bf(acc3.w);
  ushort4* o = (ushort4*)(Y + (size_t)row * 16);
  o[0] = o0; o[1] = o1; o[2] = o2; o[3] = o3;
}

// ---------------------------------------------------------------- hop at D=16 (bf16 in) + b2 + log_softmax
__global__ __launch_bounds__(256) void k_hop16(const unsigned short* __restrict__ Y,
    const float* __restrict__ b2, float* __restrict__ out,
    const int* __restrict__ offs, const int* __restrict__ csr, int n) {
  int wid = (blockIdx.x * 256 + threadIdx.x) >> 6;
  if (wid >= n) return;
  int lane = threadIdx.x & 63;
  int sub = lane >> 4, dim = lane & 15;
  int beg = offs[wid], end = offs[wid + 1];
  float acc = 0.f;
  for (int e = beg; e < end; e += 8) {
    int i0 = e + sub, i1 = e + 4 + sub;
    float v0 = 0.f, v1 = 0.f;
    if (i0 < end) v0 = bf2f(Y[(size_t)csr[i0] * 16 + dim]);
    if (i1 < end) v1 = bf2f(Y[(size_t)csr[i1] * 16 + dim]);
    acc += v0 + v1;
  }
  acc += __shfl_down(acc, 32, 64);
  acc += __shfl_down(acc, 16, 64);
  float v = acc + bf2f(Y[(size_t)wid * 16 + dim]) + b2[dim];
  float m = v;
#pragma unroll
  for (int d = 8; d >= 1; d >>= 1) m = fmaxf(m, __shfl_xor(m, d, 16));
  float s = expf(v - m);
#pragma unroll
  for (int d = 8; d >= 1; d >>= 1) s += __shfl_xor(s, d, 16);
  float r = v - (m + logf(s));
  if (lane < 16) out[(size_t)wid * 16 + dim] = r;
}

// ---------------------------------------------------------------- launch
extern "C" void kernel_launch(void* const* d_in, const int* in_sizes, int n_in,
                              void* d_out, int out_size, void* d_ws, size_t ws_size,
                              hipStream_t stream) {
  const float* x   = (const float*)d_in[0];
  const int* esrc  = (const int*)d_in[1];
  const int* edst  = (const int*)d_in[2];
  const float* W1  = (const float*)d_in[3];
  // d_in[4] = b1: cancels exactly under batchnorm mean subtraction
  const float* bnw = (const float*)d_in[5];
  const float* bnb = (const float*)d_in[6];
  const float* W2  = (const float*)d_in[7];
  const float* b2  = (const float*)d_in[8];
  float* out = (float*)d_out;

  const int N = in_sizes[0] / 128;  // 100000
  const int E = in_sizes[1];        // 1600000
  const int NB = (N + BNODES - 1) >> BSHIFT;  // 196 buckets

  char* p = (char*)d_ws;
  auto alloc = [&](size_t bytes) {
    char* q = p;
    p += (bytes + 255) & ~(size_t)255;
    return q;
  };
  int* cursor  = (int*)alloc(256 * sizeof(int));
  int* binned  = (int*)alloc((size_t)NB * CAP * sizeof(int));
  int* offs    = (int*)alloc((size_t)(N + 4) * sizeof(int));
  int* csr     = (int*)alloc((size_t)E * sizeof(int));
  float* stats = (float*)alloc((size_t)NSLOT * 128 * sizeof(float));
  float* ab    = (float*)alloc(128 * sizeof(float));
  unsigned short* h1 = (unsigned short*)alloc((size_t)N * 64 * sizeof(unsigned short));
  unsigned short* h2 = (unsigned short*)alloc((size_t)N * 64 * sizeof(unsigned short));
  unsigned short* h3 = (unsigned short*)alloc((size_t)N * 64 * sizeof(unsigned short));
  unsigned short* Yb = (unsigned short*)alloc((size_t)N * 16 * sizeof(unsigned short));

  hipMemsetAsync(cursor, 0, 256 * sizeof(int), stream);
  hipMemsetAsync(stats, 0, (size_t)NSLOT * 128 * sizeof(float), stream);

  // CSR build: bin -> per-bucket build (bucket scan folded into k_build)
  k_bin<<<(E + CHUNK - 1) / CHUNK, 256, 0, stream>>>(esrc, edst, cursor, binned, E);
  k_build<<<NB, 256, 0, stream>>>(binned, cursor, offs, csr, N, NB, E);

  // GEMM first (propagation commutes with the linear layer): hops run at D=64 bf16
  k_gemm1<<<(N + 63) / 64, 256, 0, stream>>>(x, W1, h1, N);

  int hopBlocks = (N * 64 + 255) / 256;  // one wave per node
  k_hop64b<<<hopBlocks, 256, 0, stream>>>(h1, h2, offs, csr, N, E);
  k_hop64b_stats<<<hopBlocks, 256, 0, stream>>>(h2, h3, offs, csr, stats, N, E);

  k_finalize_stats<<<1, 64, 0, stream>>>(stats, bnw, bnb, ab, N);

  // GEMM2 (with fused BN+SELU) before the last hop: hop runs at D=16 bf16
  k_gemm2<<<(N + 255) / 256, 256, 0, stream>>>(h3, ab, W2, Yb, N);
  k_hop16<<<hopBlocks, 256, 0, stream>>>(Yb, b2, out, offs, csr, N);
}

// Round 7
// 258.463 us; speedup vs baseline: 3.3077x; 1.0225x over previous
//
#include <hip/hip_runtime.h>
#include <math.h>

#define SELU_LAMBDA 1.0507009873554805f
#define SELU_ALPHA  1.6732632423543772f

#define BSHIFT 9
#define BNODES 512          // nodes per bucket
#define CAP    10240        // bucket capacity (mean 8192, +22 sigma)
#define CHUNK  4096         // edges per k_bin block
#define NSLOT  64           // stats atomic spreading slots

// bf16 helpers (round-to-nearest-even via bias trick; inputs are finite)
__device__ __forceinline__ unsigned short f2bf(float f) {
  unsigned int u = __float_as_uint(f);
  u += 0x7FFF + ((u >> 16) & 1);
  return (unsigned short)(u >> 16);
}
__device__ __forceinline__ float bf2f(unsigned short u) {
  return __uint_as_float(((unsigned int)u) << 16);
}

// ---------------------------------------------------------------- phase 1: bin edges by dst bucket
// packed entry: src | (dstLocal << 17)   (src < 2^17, dstLocal < 2^9)
__global__ __launch_bounds__(256) void k_bin(const int* __restrict__ src,
    const int* __restrict__ dst, int* __restrict__ cursor,
    int* __restrict__ binned, int e) {
  __shared__ int hist[256];
  __shared__ int gb[256];
  const int tid = threadIdx.x;
  hist[tid] = 0;
  __syncthreads();
  const int base = blockIdx.x * CHUNK;
  int bk[16], rk[16], pk[16];
#pragma unroll
  for (int k = 0; k < 16; ++k) {
    int i = base + k * 256 + tid;
    if (i < e) {
      int d = dst[i];
      int s = src[i];
      int b = d >> BSHIFT;
      bk[k] = b;
      pk[k] = s | ((d & (BNODES - 1)) << 17);
      rk[k] = atomicAdd(&hist[b], 1);
    } else {
      bk[k] = -1;
    }
  }
  __syncthreads();
  int h = hist[tid];
  if (h > 0) gb[tid] = atomicAdd(&cursor[tid], h);
  __syncthreads();
#pragma unroll
  for (int k = 0; k < 16; ++k) {
    if (bk[k] >= 0) binned[bk[k] * CAP + gb[bk[k]] + rk[k]] = pk[k];
  }
}

// ---------------------------------------------------------------- phase 2: per-bucket CSR build (one wg owns one bucket)
// bucket-count scan replicated per block (196 entries, trivial)
__global__ __launch_bounds__(256) void k_build(const int* __restrict__ binned,
    const int* __restrict__ cursor, int* __restrict__ offs,
    int* __restrict__ csr, int n, int nb, int etot) {
  __shared__ int sc[2][256];
  __shared__ int deg[BNODES];
  __shared__ int pre[BNODES];
  __shared__ int wsum[4];
  __shared__ int stage[CAP];
  __shared__ int s_cbase;
  const int b = blockIdx.x;
  const int tid = threadIdx.x;

  // replicated inclusive scan of the nb bucket counts
  int v0 = (tid < nb) ? cursor[tid] : 0;
  sc[0][tid] = v0;
  __syncthreads();
  int cur = 0;
  for (int d = 1; d < 256; d <<= 1) {
    int t = sc[cur][tid];
    if (tid >= d) t += sc[cur][tid - d];
    sc[cur ^ 1][tid] = t;
    cur ^= 1;
    __syncthreads();
  }
  if (tid == 0) {
    s_cbase = (b == 0) ? 0 : sc[cur][b - 1];
    if (b == 0) offs[n] = etot;
  }
  deg[tid] = 0;
  deg[tid + 256] = 0;
  __syncthreads();
  const int cbase = s_cbase;
  const int cnt = sc[cur][b] - cbase;

  const int nodeBase = b << BSHIFT;
  const int* gsrc = binned + b * CAP;

  for (int i = tid; i < cnt; i += 256) atomicAdd(&deg[gsrc[i] >> 17], 1);
  __syncthreads();

  // exclusive scan of deg[512]: 2 elements/thread
  const int lane = tid & 63, w = tid >> 6;
  int a0 = deg[2 * tid], a1 = deg[2 * tid + 1];
  int ps = a0 + a1;
  int s = ps;
#pragma unroll
  for (int d = 1; d < 64; d <<= 1) {
    int t = __shfl_up(s, d, 64);
    if (lane >= d) s += t;
  }
  if (lane == 63) wsum[w] = s;
  __syncthreads();
  if (tid == 0) {
    int acc = 0;
#pragma unroll
    for (int j = 0; j < 4; ++j) { int t = wsum[j]; wsum[j] = acc; acc += t; }
  }
  __syncthreads();
  int ex = wsum[w] + s - ps;
  pre[2 * tid] = ex;
  pre[2 * tid + 1] = ex + a0;
  // reset deg for use as cursor
  deg[tid] = 0;
  deg[tid + 256] = 0;
  __syncthreads();

  const int nNodes = min(BNODES, n - nodeBase);
  for (int i = tid; i < nNodes; i += 256) offs[nodeBase + i] = cbase + pre[i];

  for (int i = tid; i < cnt; i += 256) {
    int v = gsrc[i];
    int dl = v >> 17;
    int p = pre[dl] + atomicAdd(&deg[dl], 1);
    stage[p] = v & 0x1FFFF;
  }
  __syncthreads();
  for (int i = tid; i < cnt; i += 256) csr[cbase + i] = stage[i];
}

// ---------------------------------------------------------------- GEMM1: X(Nx128) @ W1(128x64) -> H1(Nx64) in bf16
__global__ __launch_bounds__(256) void k_gemm1(
    const float* __restrict__ A, const float* __restrict__ W1,
    unsigned short* __restrict__ H, int n) {
  __shared__ float Ws[128 * 64];
  for (int t = threadIdx.x; t < 128 * 64; t += 256) Ws[t] = W1[t];
  __syncthreads();

  const int rg = threadIdx.x >> 4;
  const int c0 = (threadIdx.x & 15) * 4;
  const int row0 = blockIdx.x * 64 + rg * 4;

  float acc[4][4] = {};
  for (int k = 0; k < 128; k += 4) {
    float4 a[4];
#pragma unroll
    for (int r = 0; r < 4; ++r) {
      int row = row0 + r;
      int rowc = row < n ? row : n - 1;
      a[r] = *(const float4*)&A[(size_t)rowc * 128 + k];
    }
    float4 w0 = *(const float4*)&Ws[(k + 0) * 64 + c0];
    float4 w1 = *(const float4*)&Ws[(k + 1) * 64 + c0];
    float4 w2 = *(const float4*)&Ws[(k + 2) * 64 + c0];
    float4 w3 = *(const float4*)&Ws[(k + 3) * 64 + c0];
#pragma unroll
    for (int r = 0; r < 4; ++r) {
      acc[r][0] += a[r].x * w0.x + a[r].y * w1.x + a[r].z * w2.x + a[r].w * w3.x;
      acc[r][1] += a[r].x * w0.y + a[r].y * w1.y + a[r].z * w2.y + a[r].w * w3.y;
      acc[r][2] += a[r].x * w0.z + a[r].y * w1.z + a[r].z * w2.z + a[r].w * w3.z;
      acc[r][3] += a[r].x * w0.w + a[r].y * w1.w + a[r].z * w2.w + a[r].w * w3.w;
    }
  }
#pragma unroll
  for (int r = 0; r < 4; ++r) {
    int row = row0 + r;
    if (row < n) {
      ushort4 o;
      o.x = f2bf(acc[r][0]); o.y = f2bf(acc[r][1]);
      o.z = f2bf(acc[r][2]); o.w = f2bf(acc[r][3]);
      *(ushort4*)&H[(size_t)row * 64 + c0] = o;
    }
  }
}

// ---------------------------------------------------------------- hop at D=64 (bf16 in/out)
// one wave per node; 4 sub-groups of 16 lanes; each lane loads ushort4 (4 dims)
// -> one gather instruction covers 4 edges. Short batches pad with zero row n.
__device__ __forceinline__ void hop64_gather4(const unsigned short* __restrict__ hin,
    const int* __restrict__ csr, int beg, int end, int sub, int t, int npad,
    float acc[4]) {
  acc[0] = 0.f; acc[1] = 0.f; acc[2] = 0.f; acc[3] = 0.f;
  for (int eb = beg; eb < end; eb += 16) {
    int idx[4];
#pragma unroll
    for (int k = 0; k < 4; ++k) {
      int a = eb + k * 4 + sub;
      idx[k] = (a < end) ? csr[a] : npad;   // pad -> zero row, no masking needed
    }
    ushort4 v[4];
#pragma unroll
    for (int k = 0; k < 4; ++k)
      v[k] = *(const ushort4*)&hin[(size_t)idx[k] * 64 + 4 * t];
#pragma unroll
    for (int k = 0; k < 4; ++k) {
      acc[0] += bf2f(v[k].x);
      acc[1] += bf2f(v[k].y);
      acc[2] += bf2f(v[k].z);
      acc[3] += bf2f(v[k].w);
    }
  }
}

__global__ __launch_bounds__(256) void k_hop64b(const unsigned short* __restrict__ hin,
    unsigned short* __restrict__ hout, const int* __restrict__ offs,
    const int* __restrict__ csr, int n) {
  int wid = (blockIdx.x * 256 + threadIdx.x) >> 6;
  if (wid >= n) return;
  int lane = threadIdx.x & 63;
  int sub = lane >> 4, t = lane & 15;
  int beg = offs[wid], end = offs[wid + 1];
  float acc[4];
  hop64_gather4(hin, csr, beg, end, sub, t, n, acc);
#pragma unroll
  for (int i = 0; i < 4; ++i) {
    acc[i] += __shfl_down(acc[i], 32, 64);
    acc[i] += __shfl_down(acc[i], 16, 64);
  }
  if (sub == 0) {
    ushort4 sv = *(const ushort4*)&hin[(size_t)wid * 64 + 4 * t];
    acc[0] += bf2f(sv.x); acc[1] += bf2f(sv.y);
    acc[2] += bf2f(sv.z); acc[3] += bf2f(sv.w);
    ushort4 o;
    o.x = f2bf(acc[0]); o.y = f2bf(acc[1]);
    o.z = f2bf(acc[2]); o.w = f2bf(acc[3]);
    *(ushort4*)&hout[(size_t)wid * 64 + 4 * t] = o;
  }
}

// hop2: bf16 in -> bf16 out, fused per-column (sum, sumsq) batch stats (fp32, pre-rounding)
__global__ __launch_bounds__(256) void k_hop64b_stats(const unsigned short* __restrict__ hin,
    unsigned short* __restrict__ hout, const int* __restrict__ offs,
    const int* __restrict__ csr, float* __restrict__ stats, int n) {
  int wid = (blockIdx.x * 256 + threadIdx.x) >> 6;
  int lane = threadIdx.x & 63;
  int sub = lane >> 4, t = lane & 15;
  float acc[4] = {0.f, 0.f, 0.f, 0.f};
  if (wid < n) {
    int beg = offs[wid], end = offs[wid + 1];
    hop64_gather4(hin, csr, beg, end, sub, t, n, acc);
#pragma unroll
    for (int i = 0; i < 4; ++i) {
      acc[i] += __shfl_down(acc[i], 32, 64);
      acc[i] += __shfl_down(acc[i], 16, 64);
    }
    if (sub == 0) {
      ushort4 sv = *(const ushort4*)&hin[(size_t)wid * 64 + 4 * t];
      acc[0] += bf2f(sv.x); acc[1] += bf2f(sv.y);
      acc[2] += bf2f(sv.z); acc[3] += bf2f(sv.w);
      ushort4 o;
      o.x = f2bf(acc[0]); o.y = f2bf(acc[1]);
      o.z = f2bf(acc[2]); o.w = f2bf(acc[3]);
      *(ushort4*)&hout[(size_t)wid * 64 + 4 * t] = o;
    }
  }
  __shared__ float l1[4][64];
  __shared__ float l2[4][64];
  const int w = threadIdx.x >> 6;
  if (sub == 0) {
    bool ok = (wid < n);
    float4 v1, v2;
    v1.x = ok ? acc[0] : 0.f; v1.y = ok ? acc[1] : 0.f;
    v1.z = ok ? acc[2] : 0.f; v1.w = ok ? acc[3] : 0.f;
    v2.x = v1.x * v1.x; v2.y = v1.y * v1.y;
    v2.z = v1.z * v1.z; v2.w = v1.w * v1.w;
    *(float4*)&l1[w][4 * t] = v1;
    *(float4*)&l2[w][4 * t] = v2;
  }
  __syncthreads();
  if (threadIdx.x < 64) {
    float t1 = l1[0][threadIdx.x] + l1[1][threadIdx.x] + l1[2][threadIdx.x] + l1[3][threadIdx.x];
    float t2 = l2[0][threadIdx.x] + l2[1][threadIdx.x] + l2[2][threadIdx.x] + l2[3][threadIdx.x];
    float* slot = stats + (size_t)(blockIdx.x & (NSLOT - 1)) * 128;
    atomicAdd(&slot[threadIdx.x], t1);
    atomicAdd(&slot[64 + threadIdx.x], t2);
  }
}

__global__ void k_finalize_stats(const float* __restrict__ stats,
    const float* __restrict__ bn_w, const float* __restrict__ bn_b,
    float* __restrict__ ab, int n) {
  int f = threadIdx.x;
  if (f < 64) {
    float s1 = 0.f, s2 = 0.f;
#pragma unroll 4
    for (int j = 0; j < NSLOT; ++j) {
      s1 += stats[(size_t)j * 128 + f];
      s2 += stats[(size_t)j * 128 + 64 + f];
    }
    float inv_n = 1.0f / (float)n;
    float mu = s1 * inv_n;
    float var = s2 * inv_n - mu * mu;
    float s = bn_w[f] * rsqrtf(var + 1e-5f);
    ab[f] = s;
    ab[64 + f] = bn_b[f] - mu * s;
  }
}

// ---------------------------------------------------------------- GEMM2 (bf16 in) with fused BN affine + SELU -> Y bf16 (Nx16)
__global__ __launch_bounds__(256) void k_gemm2(const unsigned short* __restrict__ A,
    const float* __restrict__ ab, const float* __restrict__ W2,
    unsigned short* __restrict__ Y, int n) {
  int row = blockIdx.x * 256 + threadIdx.x;
  if (row >= n) return;
  float4 acc0 = make_float4(0, 0, 0, 0), acc1 = acc0, acc2 = acc0, acc3 = acc0;
  const uint4* A4 = (const uint4*)(A + (size_t)row * 64);
#pragma unroll
  for (int kb = 0; kb < 8; ++kb) {
    uint4 a = A4[kb];
    unsigned int pk[4] = {a.x, a.y, a.z, a.w};
#pragma unroll
    for (int q = 0; q < 8; ++q) {
      int k = kb * 8 + q;
      unsigned int word = pk[q >> 1];
      float f = bf2f((unsigned short)((q & 1) ? (word >> 16) : (word & 0xFFFFu)));
      float y = ab[k] * f + ab[64 + k];
      y = y > 0.f ? SELU_LAMBDA * y : SELU_LAMBDA * SELU_ALPHA * expm1f(y);
      const float4* Wr = (const float4*)&W2[k * 16];
      float4 w0 = Wr[0], w1 = Wr[1], w2 = Wr[2], w3 = Wr[3];
      acc0.x += y * w0.x; acc0.y += y * w0.y; acc0.z += y * w0.z; acc0.w += y * w0.w;
      acc1.x += y * w1.x; acc1.y += y * w1.y; acc1.z += y * w1.z; acc1.w += y * w1.w;
      acc2.x += y * w2.x; acc2.y += y * w2.y; acc2.z += y * w2.z; acc2.w += y * w2.w;
      acc3.x += y * w3.x; acc3.y += y * w3.y; acc3.z += y * w3.z; acc3.w += y * w3.w;
    }
  }
  ushort4 o0, o1, o2, o3;
  o0.x = f2bf(acc0.x); o0.y = f2bf(acc0.y); o0.z = f2bf(acc0.z); o0.w = f2bf(acc0.w);
  o1.x = f2bf(acc1.x); o1.y = f2bf(acc1.y); o1.z = f2bf(acc1.z); o1.w = f2bf(acc1.w);
  o2.x = f2bf(acc2.x); o2.y = f2bf(acc2.y); o2.z = f2bf(acc2.z); o2.w = f2bf(acc2.w);
  o3.x = f2bf(acc3.x); o3.y = f2bf(acc3.y); o3.z = f2bf(acc3.z); o3.w = f2bf(acc3.w);
  ushort4* o = (ushort4*)(Y + (size_t)row * 16);
  o[0] = o0; o[1] = o1; o[2] = o2; o[3] = o3;
}

// ---------------------------------------------------------------- hop at D=16 (bf16 in) + b2 + log_softmax
__global__ __launch_bounds__(256) void k_hop16(const unsigned short* __restrict__ Y,
    const float* __restrict__ b2, float* __restrict__ out,
    const int* __restrict__ offs, const int* __restrict__ csr, int n) {
  int wid = (blockIdx.x * 256 + threadIdx.x) >> 6;
  if (wid >= n) return;
  int lane = threadIdx.x & 63;
  int sub = lane >> 4, dim = lane & 15;
  int beg = offs[wid], end = offs[wid + 1];
  float acc = 0.f;
  for (int e = beg; e < end; e += 8) {
    int i0 = e + sub, i1 = e + 4 + sub;
    float v0 = 0.f, v1 = 0.f;
    if (i0 < end) v0 = bf2f(Y[(size_t)csr[i0] * 16 + dim]);
    if (i1 < end) v1 = bf2f(Y[(size_t)csr[i1] * 16 + dim]);
    acc += v0 + v1;
  }
  acc += __shfl_down(acc, 32, 64);
  acc += __shfl_down(acc, 16, 64);
  float v = acc + bf2f(Y[(size_t)wid * 16 + dim]) + b2[dim];
  float m = v;
#pragma unroll
  for (int d = 8; d >= 1; d >>= 1) m = fmaxf(m, __shfl_xor(m, d, 16));
  float s = expf(v - m);
#pragma unroll
  for (int d = 8; d >= 1; d >>= 1) s += __shfl_xor(s, d, 16);
  float r = v - (m + logf(s));
  if (lane < 16) out[(size_t)wid * 16 + dim] = r;
}

// ---------------------------------------------------------------- launch
extern "C" void kernel_launch(void* const* d_in, const int* in_sizes, int n_in,
                              void* d_out, int out_size, void* d_ws, size_t ws_size,
                              hipStream_t stream) {
  const float* x   = (const float*)d_in[0];
  const int* esrc  = (const int*)d_in[1];
  const int* edst  = (const int*)d_in[2];
  const float* W1  = (const float*)d_in[3];
  // d_in[4] = b1: cancels exactly under batchnorm mean subtraction
  const float* bnw = (const float*)d_in[5];
  const float* bnb = (const float*)d_in[6];
  const float* W2  = (const float*)d_in[7];
  const float* b2  = (const float*)d_in[8];
  float* out = (float*)d_out;

  const int N = in_sizes[0] / 128;  // 100000
  const int E = in_sizes[1];        // 1600000
  const int NB = (N + BNODES - 1) >> BSHIFT;  // 196 buckets

  char* p = (char*)d_ws;
  auto alloc = [&](size_t bytes) {
    char* q = p;
    p += (bytes + 255) & ~(size_t)255;
    return q;
  };
  int* cursor  = (int*)alloc(256 * sizeof(int));
  int* binned  = (int*)alloc((size_t)NB * CAP * sizeof(int));
  int* offs    = (int*)alloc((size_t)(N + 4) * sizeof(int));
  int* csr     = (int*)alloc((size_t)E * sizeof(int));
  float* stats = (float*)alloc((size_t)NSLOT * 128 * sizeof(float));
  float* ab    = (float*)alloc(128 * sizeof(float));
  unsigned short* h1 = (unsigned short*)alloc((size_t)(N + 1) * 64 * sizeof(unsigned short));
  unsigned short* h2 = (unsigned short*)alloc((size_t)(N + 1) * 64 * sizeof(unsigned short));
  unsigned short* h3 = (unsigned short*)alloc((size_t)N * 64 * sizeof(unsigned short));
  unsigned short* Yb = (unsigned short*)alloc((size_t)N * 16 * sizeof(unsigned short));

  hipMemsetAsync(cursor, 0, 256 * sizeof(int), stream);
  hipMemsetAsync(stats, 0, (size_t)NSLOT * 128 * sizeof(float), stream);
  // zero-pad rows (index N) used by hop gather padding
  hipMemsetAsync(h1 + (size_t)N * 64, 0, 64 * sizeof(unsigned short), stream);
  hipMemsetAsync(h2 + (size_t)N * 64, 0, 64 * sizeof(unsigned short), stream);

  // CSR build: bin -> per-bucket build (bucket scan folded into k_build)
  k_bin<<<(E + CHUNK - 1) / CHUNK, 256, 0, stream>>>(esrc, edst, cursor, binned, E);
  k_build<<<NB, 256, 0, stream>>>(binned, cursor, offs, csr, N, NB, E);

  // GEMM first (propagation commutes with the linear layer): hops run at D=64 bf16
  k_gemm1<<<(N + 63) / 64, 256, 0, stream>>>(x, W1, h1, N);

  int hopBlocks = (N * 64 + 255) / 256;  // one wave per node
  k_hop64b<<<hopBlocks, 256, 0, stream>>>(h1, h2, offs, csr, N);
  k_hop64b_stats<<<hopBlocks, 256, 0, stream>>>(h2, h3, offs, csr, stats, N);

  k_finalize_stats<<<1, 64, 0, stream>>>(stats, bnw, bnb, ab, N);

  // GEMM2 (with fused BN+SELU) before the last hop: hop runs at D=16 bf16
  k_gemm2<<<(N + 255) / 256, 256, 0, stream>>>(h3, ab, W2, Yb, N);
  k_hop16<<<hopBlocks, 256, 0, stream>>>(Yb, b2, out, offs, csr, N);
}

// Round 8
// 242.712 us; speedup vs baseline: 3.5223x; 1.0649x over previous
//
#include <hip/hip_runtime.h>
#include <math.h>

#define SELU_LAMBDA 1.0507009873554805f
#define SELU_ALPHA  1.6732632423543772f

#define BSHIFT 9
#define BNODES 512          // nodes per bucket
#define CAP    10240        // bucket capacity (mean 8192, +22 sigma)
#define CHUNK  4096         // edges per k_bin block
#define NSLOT  64           // stats atomic spreading slots

// bf16 helpers (round-to-nearest-even via bias trick; inputs are finite)
__device__ __forceinline__ unsigned short f2bf(float f) {
  unsigned int u = __float_as_uint(f);
  u += 0x7FFF + ((u >> 16) & 1);
  return (unsigned short)(u >> 16);
}
__device__ __forceinline__ float bf2f(unsigned short u) {
  return __uint_as_float(((unsigned int)u) << 16);
}

// ---------------------------------------------------------------- setup: zero cursor/stats/pad rows (replaces 4 memsets)
__global__ __launch_bounds__(256) void k_zero(int* __restrict__ cursor,
    float* __restrict__ stats, unsigned short* __restrict__ h1pad,
    unsigned short* __restrict__ h2pad, unsigned short* __restrict__ ybpad) {
  int i = blockIdx.x * 256 + threadIdx.x;
  if (i < 256) cursor[i] = 0;
  if (i < NSLOT * 128) stats[i] = 0.f;
  if (i < 64) { h1pad[i] = 0; h2pad[i] = 0; }
  if (i < 16) ybpad[i] = 0;
}

// ---------------------------------------------------------------- phase 1: bin edges by dst bucket
// packed entry: src | (dstLocal << 17)   (src < 2^17, dstLocal < 2^9)
__global__ __launch_bounds__(256) void k_bin(const int* __restrict__ src,
    const int* __restrict__ dst, int* __restrict__ cursor,
    int* __restrict__ binned, int e) {
  __shared__ int hist[256];
  __shared__ int gb[256];
  const int tid = threadIdx.x;
  hist[tid] = 0;
  __syncthreads();
  const int base = blockIdx.x * CHUNK;
  int bk[16], rk[16], pk[16];
#pragma unroll
  for (int k = 0; k < 16; ++k) {
    int i = base + k * 256 + tid;
    if (i < e) {
      int d = dst[i];
      int s = src[i];
      int b = d >> BSHIFT;
      bk[k] = b;
      pk[k] = s | ((d & (BNODES - 1)) << 17);
      rk[k] = atomicAdd(&hist[b], 1);
    } else {
      bk[k] = -1;
    }
  }
  __syncthreads();
  int h = hist[tid];
  if (h > 0) gb[tid] = atomicAdd(&cursor[tid], h);
  __syncthreads();
#pragma unroll
  for (int k = 0; k < 16; ++k) {
    if (bk[k] >= 0) binned[bk[k] * CAP + gb[bk[k]] + rk[k]] = pk[k];
  }
}

// ---------------------------------------------------------------- phase 2: per-bucket CSR build (one wg owns one bucket)
// bucket-count scan replicated per block (196 entries, trivial)
__global__ __launch_bounds__(256) void k_build(const int* __restrict__ binned,
    const int* __restrict__ cursor, int* __restrict__ offs,
    int* __restrict__ csr, int n, int nb, int etot) {
  __shared__ int sc[2][256];
  __shared__ int deg[BNODES];
  __shared__ int pre[BNODES];
  __shared__ int wsum[4];
  __shared__ int stage[CAP];
  __shared__ int s_cbase;
  const int b = blockIdx.x;
  const int tid = threadIdx.x;

  // replicated inclusive scan of the nb bucket counts
  int v0 = (tid < nb) ? cursor[tid] : 0;
  sc[0][tid] = v0;
  __syncthreads();
  int cur = 0;
  for (int d = 1; d < 256; d <<= 1) {
    int t = sc[cur][tid];
    if (tid >= d) t += sc[cur][tid - d];
    sc[cur ^ 1][tid] = t;
    cur ^= 1;
    __syncthreads();
  }
  if (tid == 0) {
    s_cbase = (b == 0) ? 0 : sc[cur][b - 1];
    if (b == 0) offs[n] = etot;
  }
  deg[tid] = 0;
  deg[tid + 256] = 0;
  __syncthreads();
  const int cbase = s_cbase;
  const int cnt = sc[cur][b] - cbase;

  const int nodeBase = b << BSHIFT;
  const int* gsrc = binned + b * CAP;

  for (int i = tid; i < cnt; i += 256) atomicAdd(&deg[gsrc[i] >> 17], 1);
  __syncthreads();

  // exclusive scan of deg[512]: 2 elements/thread
  const int lane = tid & 63, w = tid >> 6;
  int a0 = deg[2 * tid], a1 = deg[2 * tid + 1];
  int ps = a0 + a1;
  int s = ps;
#pragma unroll
  for (int d = 1; d < 64; d <<= 1) {
    int t = __shfl_up(s, d, 64);
    if (lane >= d) s += t;
  }
  if (lane == 63) wsum[w] = s;
  __syncthreads();
  if (tid == 0) {
    int acc = 0;
#pragma unroll
    for (int j = 0; j < 4; ++j) { int t = wsum[j]; wsum[j] = acc; acc += t; }
  }
  __syncthreads();
  int ex = wsum[w] + s - ps;
  pre[2 * tid] = ex;
  pre[2 * tid + 1] = ex + a0;
  // reset deg for use as cursor
  deg[tid] = 0;
  deg[tid + 256] = 0;
  __syncthreads();

  const int nNodes = min(BNODES, n - nodeBase);
  for (int i = tid; i < nNodes; i += 256) offs[nodeBase + i] = cbase + pre[i];

  for (int i = tid; i < cnt; i += 256) {
    int v = gsrc[i];
    int dl = v >> 17;
    int p = pre[dl] + atomicAdd(&deg[dl], 1);
    stage[p] = v & 0x1FFFF;
  }
  __syncthreads();
  for (int i = tid; i < cnt; i += 256) csr[cbase + i] = stage[i];
}

// ---------------------------------------------------------------- GEMM1: X(Nx128) @ W1(128x64) -> H1(Nx64) in bf16
__global__ __launch_bounds__(256) void k_gemm1(
    const float* __restrict__ A, const float* __restrict__ W1,
    unsigned short* __restrict__ H, int n) {
  __shared__ float Ws[128 * 64];
  for (int t = threadIdx.x; t < 128 * 64; t += 256) Ws[t] = W1[t];
  __syncthreads();

  const int rg = threadIdx.x >> 4;
  const int c0 = (threadIdx.x & 15) * 4;
  const int row0 = blockIdx.x * 64 + rg * 4;

  float acc[4][4] = {};
  for (int k = 0; k < 128; k += 4) {
    float4 a[4];
#pragma unroll
    for (int r = 0; r < 4; ++r) {
      int row = row0 + r;
      int rowc = row < n ? row : n - 1;
      a[r] = *(const float4*)&A[(size_t)rowc * 128 + k];
    }
    float4 w0 = *(const float4*)&Ws[(k + 0) * 64 + c0];
    float4 w1 = *(const float4*)&Ws[(k + 1) * 64 + c0];
    float4 w2 = *(const float4*)&Ws[(k + 2) * 64 + c0];
    float4 w3 = *(const float4*)&Ws[(k + 3) * 64 + c0];
#pragma unroll
    for (int r = 0; r < 4; ++r) {
      acc[r][0] += a[r].x * w0.x + a[r].y * w1.x + a[r].z * w2.x + a[r].w * w3.x;
      acc[r][1] += a[r].x * w0.y + a[r].y * w1.y + a[r].z * w2.y + a[r].w * w3.y;
      acc[r][2] += a[r].x * w0.z + a[r].y * w1.z + a[r].z * w2.z + a[r].w * w3.z;
      acc[r][3] += a[r].x * w0.w + a[r].y * w1.w + a[r].z * w2.w + a[r].w * w3.w;
    }
  }
#pragma unroll
  for (int r = 0; r < 4; ++r) {
    int row = row0 + r;
    if (row < n) {
      ushort4 o;
      o.x = f2bf(acc[r][0]); o.y = f2bf(acc[r][1]);
      o.z = f2bf(acc[r][2]); o.w = f2bf(acc[r][3]);
      *(ushort4*)&H[(size_t)row * 64 + c0] = o;
    }
  }
}

// ---------------------------------------------------------------- hop at D=64 (bf16 in/out)
// one wave per node; 4 sub-groups of 16 lanes; each lane loads ushort4 (4 dims)
// -> one gather instruction covers 4 edges. Short batches pad with zero row n.
__device__ __forceinline__ void hop64_gather4(const unsigned short* __restrict__ hin,
    const int* __restrict__ csr, int beg, int end, int sub, int t, int npad,
    float acc[4]) {
  acc[0] = 0.f; acc[1] = 0.f; acc[2] = 0.f; acc[3] = 0.f;
  for (int eb = beg; eb < end; eb += 16) {
    int idx[4];
#pragma unroll
    for (int k = 0; k < 4; ++k) {
      int a = eb + k * 4 + sub;
      idx[k] = (a < end) ? csr[a] : npad;   // pad -> zero row, no masking needed
    }
    ushort4 v[4];
#pragma unroll
    for (int k = 0; k < 4; ++k)
      v[k] = *(const ushort4*)&hin[(size_t)idx[k] * 64 + 4 * t];
#pragma unroll
    for (int k = 0; k < 4; ++k) {
      acc[0] += bf2f(v[k].x);
      acc[1] += bf2f(v[k].y);
      acc[2] += bf2f(v[k].z);
      acc[3] += bf2f(v[k].w);
    }
  }
}

__global__ __launch_bounds__(256) void k_hop64b(const unsigned short* __restrict__ hin,
    unsigned short* __restrict__ hout, const int* __restrict__ offs,
    const int* __restrict__ csr, int n) {
  int wid = (blockIdx.x * 256 + threadIdx.x) >> 6;
  if (wid >= n) return;
  int lane = threadIdx.x & 63;
  int sub = lane >> 4, t = lane & 15;
  int beg = offs[wid], end = offs[wid + 1];
  float acc[4];
  hop64_gather4(hin, csr, beg, end, sub, t, n, acc);
#pragma unroll
  for (int i = 0; i < 4; ++i) {
    acc[i] += __shfl_down(acc[i], 32, 64);
    acc[i] += __shfl_down(acc[i], 16, 64);
  }
  if (sub == 0) {
    ushort4 sv = *(const ushort4*)&hin[(size_t)wid * 64 + 4 * t];
    acc[0] += bf2f(sv.x); acc[1] += bf2f(sv.y);
    acc[2] += bf2f(sv.z); acc[3] += bf2f(sv.w);
    ushort4 o;
    o.x = f2bf(acc[0]); o.y = f2bf(acc[1]);
    o.z = f2bf(acc[2]); o.w = f2bf(acc[3]);
    *(ushort4*)&hout[(size_t)wid * 64 + 4 * t] = o;
  }
}

// hop2: bf16 in -> bf16 out, fused per-column (sum, sumsq) batch stats (fp32, pre-rounding)
__global__ __launch_bounds__(256) void k_hop64b_stats(const unsigned short* __restrict__ hin,
    unsigned short* __restrict__ hout, const int* __restrict__ offs,
    const int* __restrict__ csr, float* __restrict__ stats, int n) {
  int wid = (blockIdx.x * 256 + threadIdx.x) >> 6;
  int lane = threadIdx.x & 63;
  int sub = lane >> 4, t = lane & 15;
  float acc[4] = {0.f, 0.f, 0.f, 0.f};
  if (wid < n) {
    int beg = offs[wid], end = offs[wid + 1];
    hop64_gather4(hin, csr, beg, end, sub, t, n, acc);
#pragma unroll
    for (int i = 0; i < 4; ++i) {
      acc[i] += __shfl_down(acc[i], 32, 64);
      acc[i] += __shfl_down(acc[i], 16, 64);
    }
    if (sub == 0) {
      ushort4 sv = *(const ushort4*)&hin[(size_t)wid * 64 + 4 * t];
      acc[0] += bf2f(sv.x); acc[1] += bf2f(sv.y);
      acc[2] += bf2f(sv.z); acc[3] += bf2f(sv.w);
      ushort4 o;
      o.x = f2bf(acc[0]); o.y = f2bf(acc[1]);
      o.z = f2bf(acc[2]); o.w = f2bf(acc[3]);
      *(ushort4*)&hout[(size_t)wid * 64 + 4 * t] = o;
    }
  }
  __shared__ float l1[4][64];
  __shared__ float l2[4][64];
  const int w = threadIdx.x >> 6;
  if (sub == 0) {
    bool ok = (wid < n);
    float4 v1, v2;
    v1.x = ok ? acc[0] : 0.f; v1.y = ok ? acc[1] : 0.f;
    v1.z = ok ? acc[2] : 0.f; v1.w = ok ? acc[3] : 0.f;
    v2.x = v1.x * v1.x; v2.y = v1.y * v1.y;
    v2.z = v1.z * v1.z; v2.w = v1.w * v1.w;
    *(float4*)&l1[w][4 * t] = v1;
    *(float4*)&l2[w][4 * t] = v2;
  }
  __syncthreads();
  if (threadIdx.x < 64) {
    float t1 = l1[0][threadIdx.x] + l1[1][threadIdx.x] + l1[2][threadIdx.x] + l1[3][threadIdx.x];
    float t2 = l2[0][threadIdx.x] + l2[1][threadIdx.x] + l2[2][threadIdx.x] + l2[3][threadIdx.x];
    float* slot = stats + (size_t)(blockIdx.x & (NSLOT - 1)) * 128;
    atomicAdd(&slot[threadIdx.x], t1);
    atomicAdd(&slot[64 + threadIdx.x], t2);
  }
}

__global__ void k_finalize_stats(const float* __restrict__ stats,
    const float* __restrict__ bn_w, const float* __restrict__ bn_b,
    float* __restrict__ ab, int n) {
  int f = threadIdx.x;
  if (f < 64) {
    float s1 = 0.f, s2 = 0.f;
#pragma unroll 4
    for (int j = 0; j < NSLOT; ++j) {
      s1 += stats[(size_t)j * 128 + f];
      s2 += stats[(size_t)j * 128 + 64 + f];
    }
    float inv_n = 1.0f / (float)n;
    float mu = s1 * inv_n;
    float var = s2 * inv_n - mu * mu;
    float s = bn_w[f] * rsqrtf(var + 1e-5f);
    ab[f] = s;
    ab[64 + f] = bn_b[f] - mu * s;
  }
}

// ---------------------------------------------------------------- GEMM2 (bf16 in) with fused BN affine + SELU -> Y bf16 (Nx16)
__global__ __launch_bounds__(256) void k_gemm2(const unsigned short* __restrict__ A,
    const float* __restrict__ ab, const float* __restrict__ W2,
    unsigned short* __restrict__ Y, int n) {
  int row = blockIdx.x * 256 + threadIdx.x;
  if (row >= n) return;
  float4 acc0 = make_float4(0, 0, 0, 0), acc1 = acc0, acc2 = acc0, acc3 = acc0;
  const uint4* A4 = (const uint4*)(A + (size_t)row * 64);
#pragma unroll
  for (int kb = 0; kb < 8; ++kb) {
    uint4 a = A4[kb];
    unsigned int pk[4] = {a.x, a.y, a.z, a.w};
#pragma unroll
    for (int q = 0; q < 8; ++q) {
      int k = kb * 8 + q;
      unsigned int word = pk[q >> 1];
      float f = bf2f((unsigned short)((q & 1) ? (word >> 16) : (word & 0xFFFFu)));
      float y = ab[k] * f + ab[64 + k];
      y = y > 0.f ? SELU_LAMBDA * y : SELU_LAMBDA * SELU_ALPHA * expm1f(y);
      const float4* Wr = (const float4*)&W2[k * 16];
      float4 w0 = Wr[0], w1 = Wr[1], w2 = Wr[2], w3 = Wr[3];
      acc0.x += y * w0.x; acc0.y += y * w0.y; acc0.z += y * w0.z; acc0.w += y * w0.w;
      acc1.x += y * w1.x; acc1.y += y * w1.y; acc1.z += y * w1.z; acc1.w += y * w1.w;
      acc2.x += y * w2.x; acc2.y += y * w2.y; acc2.z += y * w2.z; acc2.w += y * w2.w;
      acc3.x += y * w3.x; acc3.y += y * w3.y; acc3.z += y * w3.z; acc3.w += y * w3.w;
    }
  }
  ushort4 o0, o1, o2, o3;
  o0.x = f2bf(acc0.x); o0.y = f2bf(acc0.y); o0.z = f2bf(acc0.z); o0.w = f2bf(acc0.w);
  o1.x = f2bf(acc1.x); o1.y = f2bf(acc1.y); o1.z = f2bf(acc1.z); o1.w = f2bf(acc1.w);
  o2.x = f2bf(acc2.x); o2.y = f2bf(acc2.y); o2.z = f2bf(acc2.z); o2.w = f2bf(acc2.w);
  o3.x = f2bf(acc3.x); o3.y = f2bf(acc3.y); o3.z = f2bf(acc3.z); o3.w = f2bf(acc3.w);
  ushort4* o = (ushort4*)(Y + (size_t)row * 16);
  o[0] = o0; o[1] = o1; o[2] = o2; o[3] = o3;
}

// ---------------------------------------------------------------- hop at D=16 (bf16 in) + b2 + log_softmax
// one wave per node; 8 subgroups x 8 lanes; lane loads uint (2 dims)
// -> one gather instruction covers 8 edges. Pad with zero row n.
__global__ __launch_bounds__(256) void k_hop16(const unsigned short* __restrict__ Y,
    const float* __restrict__ b2, float* __restrict__ out,
    const int* __restrict__ offs, const int* __restrict__ csr, int n) {
  int wid = (blockIdx.x * 256 + threadIdx.x) >> 6;
  if (wid >= n) return;
  int lane = threadIdx.x & 63;
  int sub = lane >> 3, t = lane & 7;   // lane covers dims 2t, 2t+1
  int beg = offs[wid], end = offs[wid + 1];
  float a0 = 0.f, a1 = 0.f;
  for (int eb = beg; eb < end; eb += 8) {
    int a = eb + sub;
    int idx = (a < end) ? csr[a] : n;   // row n = zero pad
    unsigned int w = *(const unsigned int*)&Y[(size_t)idx * 16 + 2 * t];
    a0 += bf2f((unsigned short)(w & 0xFFFFu));
    a1 += bf2f((unsigned short)(w >> 16));
  }
  a0 += __shfl_down(a0, 32, 64); a1 += __shfl_down(a1, 32, 64);
  a0 += __shfl_down(a0, 16, 64); a1 += __shfl_down(a1, 16, 64);
  a0 += __shfl_down(a0, 8, 64);  a1 += __shfl_down(a1, 8, 64);
  if (sub == 0) {
    unsigned int sw = *(const unsigned int*)&Y[(size_t)wid * 16 + 2 * t];
    float2 bb = *(const float2*)&b2[2 * t];
    float v0 = a0 + bf2f((unsigned short)(sw & 0xFFFFu)) + bb.x;
    float v1 = a1 + bf2f((unsigned short)(sw >> 16)) + bb.y;
    float m = fmaxf(v0, v1);
#pragma unroll
    for (int d = 4; d >= 1; d >>= 1) m = fmaxf(m, __shfl_xor(m, d, 8));
    float s = expf(v0 - m) + expf(v1 - m);
#pragma unroll
    for (int d = 4; d >= 1; d >>= 1) s += __shfl_xor(s, d, 8);
    float ls = m + logf(s);
    *(float2*)&out[(size_t)wid * 16 + 2 * t] = make_float2(v0 - ls, v1 - ls);
  }
}

// ---------------------------------------------------------------- launch
extern "C" void kernel_launch(void* const* d_in, const int* in_sizes, int n_in,
                              void* d_out, int out_size, void* d_ws, size_t ws_size,
                              hipStream_t stream) {
  const float* x   = (const float*)d_in[0];
  const int* esrc  = (const int*)d_in[1];
  const int* edst  = (const int*)d_in[2];
  const float* W1  = (const float*)d_in[3];
  // d_in[4] = b1: cancels exactly under batchnorm mean subtraction
  const float* bnw = (const float*)d_in[5];
  const float* bnb = (const float*)d_in[6];
  const float* W2  = (const float*)d_in[7];
  const float* b2  = (const float*)d_in[8];
  float* out = (float*)d_out;

  const int N = in_sizes[0] / 128;  // 100000
  const int E = in_sizes[1];        // 1600000
  const int NB = (N + BNODES - 1) >> BSHIFT;  // 196 buckets

  char* p = (char*)d_ws;
  auto alloc = [&](size_t bytes) {
    char* q = p;
    p += (bytes + 255) & ~(size_t)255;
    return q;
  };
  int* cursor  = (int*)alloc(256 * sizeof(int));
  int* binned  = (int*)alloc((size_t)NB * CAP * sizeof(int));
  int* offs    = (int*)alloc((size_t)(N + 4) * sizeof(int));
  int* csr     = (int*)alloc((size_t)E * sizeof(int));
  float* stats = (float*)alloc((size_t)NSLOT * 128 * sizeof(float));
  float* ab    = (float*)alloc(128 * sizeof(float));
  unsigned short* h1 = (unsigned short*)alloc((size_t)(N + 1) * 64 * sizeof(unsigned short));
  unsigned short* h2 = (unsigned short*)alloc((size_t)(N + 1) * 64 * sizeof(unsigned short));
  unsigned short* h3 = (unsigned short*)alloc((size_t)N * 64 * sizeof(unsigned short));
  unsigned short* Yb = (unsigned short*)alloc((size_t)(N + 1) * 16 * sizeof(unsigned short));

  // one setup kernel zeroes cursor, stats, and the three zero-pad rows
  k_zero<<<(NSLOT * 128 + 255) / 256, 256, 0, stream>>>(
      cursor, stats, h1 + (size_t)N * 64, h2 + (size_t)N * 64, Yb + (size_t)N * 16);

  // CSR build: bin -> per-bucket build (bucket scan folded into k_build)
  k_bin<<<(E + CHUNK - 1) / CHUNK, 256, 0, stream>>>(esrc, edst, cursor, binned, E);
  k_build<<<NB, 256, 0, stream>>>(binned, cursor, offs, csr, N, NB, E);

  // GEMM first (propagation commutes with the linear layer): hops run at D=64 bf16
  k_gemm1<<<(N + 63) / 64, 256, 0, stream>>>(x, W1, h1, N);

  int hopBlocks = (N * 64 + 255) / 256;  // one wave per node
  k_hop64b<<<hopBlocks, 256, 0, stream>>>(h1, h2, offs, csr, N);
  k_hop64b_stats<<<hopBlocks, 256, 0, stream>>>(h2, h3, offs, csr, stats, N);

  k_finalize_stats<<<1, 64, 0, stream>>>(stats, bnw, bnb, ab, N);

  // GEMM2 (with fused BN+SELU) before the last hop: hop runs at D=16 bf16
  k_gemm2<<<(N + 255) / 256, 256, 0, stream>>>(h3, ab, W2, Yb, N);
  k_hop16<<<hopBlocks, 256, 0, stream>>>(Yb, b2, out, offs, csr, N);
}